// Round 1
// baseline (853.399 us; speedup 1.0000x reference)
//
#include <hip/hip_runtime.h>
#include <math.h>

#define N_NODES 50000
#define E_EDGES 600000
#define DD 128
#define G_GRAPHS 512
#define K_CODES 512
#define Q_QUANT 3
#define FD_OUT 512
#define NEG_SLOPE 0.2f
#define LN_EPS 1e-5f

static __device__ __forceinline__ float lrelu(float v){ return v > 0.f ? v : NEG_SLOPE*v; }

static __device__ __forceinline__ float wsum(float v){
#pragma unroll
  for (int m = 1; m < 64; m <<= 1) v += __shfl_xor(v, m);
  return v;
}
static __device__ __forceinline__ float wmax(float v){
#pragma unroll
  for (int m = 1; m < 64; m <<= 1) v = fmaxf(v, __shfl_xor(v, m));
  return v;
}

// ---------------- xl/xr transform: out[n][128] = x @ W + b ----------------
__global__ __launch_bounds__(256)
void k_xform(const float* __restrict__ x, const float* __restrict__ W,
             const float* __restrict__ bias, float* __restrict__ out, int n)
{
  __shared__ __align__(16) float xt[64*130];
  __shared__ __align__(16) float Wt[32*128];
  const int tid = threadIdx.x;
  const int r0 = blockIdx.x * 64;
  {
    const int q = tid & 63, eb = tid >> 6;
#pragma unroll
    for (int i = 0; i < 16; ++i){
      int e = eb + 4*i;
      int row = r0 + e;
      float2 v = make_float2(0.f, 0.f);
      if (row < n) v = *(const float2*)&x[row*DD + q*2];
      *(float2*)&xt[e*130 + q*2] = v;
    }
  }
  const int eg = tid >> 4;   // 0..15 -> rows eg*4..+3
  const int cg = tid & 15;   // 0..15 -> cols cg*8..+7
  float acc[4][8];
#pragma unroll
  for (int j = 0; j < 4; ++j)
#pragma unroll
    for (int u = 0; u < 8; ++u) acc[j][u] = 0.f;

  for (int kq = 0; kq < 4; ++kq){
    __syncthreads();
    {
      const int c4 = tid & 31, kb = tid >> 5;
#pragma unroll
      for (int i = 0; i < 4; ++i){
        int kk = kb + 8*i;
        *(float4*)&Wt[kk*128 + c4*4] = *(const float4*)&W[(kq*32+kk)*DD + c4*4];
      }
    }
    __syncthreads();
    const int kb2 = kq*32;
#pragma unroll 4
    for (int k = 0; k < 32; ++k){
      float aa[4];
#pragma unroll
      for (int j = 0; j < 4; ++j) aa[j] = xt[(eg*4+j)*130 + kb2 + k];
      float bb[8];
      *(float4*)&bb[0] = *(const float4*)&Wt[k*128 + cg*8];
      *(float4*)&bb[4] = *(const float4*)&Wt[k*128 + cg*8 + 4];
#pragma unroll
      for (int j = 0; j < 4; ++j)
#pragma unroll
        for (int u = 0; u < 8; ++u) acc[j][u] = fmaf(aa[j], bb[u], acc[j][u]);
    }
  }
  float bv[8];
  *(float4*)&bv[0] = *(const float4*)&bias[cg*8];
  *(float4*)&bv[4] = *(const float4*)&bias[cg*8+4];
#pragma unroll
  for (int j = 0; j < 4; ++j){
    int row = r0 + eg*4 + j;
    if (row < n){
      float o[8];
#pragma unroll
      for (int u = 0; u < 8; ++u) o[u] = acc[j][u] + bv[u];
      *(float4*)&out[row*DD + cg*8]     = *(const float4*)&o[0];
      *(float4*)&out[row*DD + cg*8 + 4] = *(const float4*)&o[4];
    }
  }
}

// --------- per-edge score: e_emb = ea@W_edge (fused), score = lrelu(e).att ---------
__global__ __launch_bounds__(256)
void k_edge(const float* __restrict__ edge_attr, const float* __restrict__ W_edge,
            const int* __restrict__ ei, const float* __restrict__ xl,
            const float* __restrict__ xr, const float* __restrict__ att,
            float* __restrict__ scores, float* __restrict__ asum_mid)
{
  __shared__ __align__(16) float ea[64*130];
  __shared__ __align__(16) float Wt[32*128];
  const int tid = threadIdx.x;
  const int e0 = blockIdx.x * 64;   // E divisible by 64
  {
    const int q = tid & 63, eb = tid >> 6;
#pragma unroll
    for (int i = 0; i < 16; ++i){
      int e = eb + 4*i;
      *(float2*)&ea[e*130 + q*2] = *(const float2*)&edge_attr[(e0+e)*DD + q*2];
    }
  }
  const int eg = tid >> 4;
  const int cg = tid & 15;
  float acc[4][8];
#pragma unroll
  for (int j = 0; j < 4; ++j)
#pragma unroll
    for (int u = 0; u < 8; ++u) acc[j][u] = 0.f;

  for (int kq = 0; kq < 4; ++kq){
    __syncthreads();
    {
      const int c4 = tid & 31, kb = tid >> 5;
#pragma unroll
      for (int i = 0; i < 4; ++i){
        int kk = kb + 8*i;
        *(float4*)&Wt[kk*128 + c4*4] = *(const float4*)&W_edge[(kq*32+kk)*DD + c4*4];
      }
    }
    __syncthreads();
    const int kb2 = kq*32;
#pragma unroll 4
    for (int k = 0; k < 32; ++k){
      float aa[4];
#pragma unroll
      for (int j = 0; j < 4; ++j) aa[j] = ea[(eg*4+j)*130 + kb2 + k];
      float bb[8];
      *(float4*)&bb[0] = *(const float4*)&Wt[k*128 + cg*8];
      *(float4*)&bb[4] = *(const float4*)&Wt[k*128 + cg*8 + 4];
#pragma unroll
      for (int j = 0; j < 4; ++j)
#pragma unroll
        for (int u = 0; u < 8; ++u) acc[j][u] = fmaf(aa[j], bb[u], acc[j][u]);
    }
  }
  // epilogue: add xl[src] + xr[dst], leaky-relu, dot with att, reduce over cg
  float attv[8];
  *(float4*)&attv[0] = *(const float4*)&att[cg*8];
  *(float4*)&attv[4] = *(const float4*)&att[cg*8+4];
  float sp[4];
#pragma unroll
  for (int j = 0; j < 4; ++j){
    int e = e0 + eg*4 + j;
    int s = ei[e];
    int d = ei[E_EDGES + e];
    float xlv[8], xrv[8];
    *(float4*)&xlv[0] = *(const float4*)&xl[s*DD + cg*8];
    *(float4*)&xlv[4] = *(const float4*)&xl[s*DD + cg*8 + 4];
    *(float4*)&xrv[0] = *(const float4*)&xr[d*DD + cg*8];
    *(float4*)&xrv[4] = *(const float4*)&xr[d*DD + cg*8 + 4];
    float p = 0.f;
#pragma unroll
    for (int u = 0; u < 8; ++u){
      float vv = acc[j][u] + xlv[u] + xrv[u];
      p += lrelu(vv) * attv[u];
    }
    sp[j] = p;
  }
#pragma unroll
  for (int m = 1; m < 16; m <<= 1){
#pragma unroll
    for (int j = 0; j < 4; ++j) sp[j] += __shfl_xor(sp[j], m);
  }
  if (cg == 0){
#pragma unroll
    for (int j = 0; j < 4; ++j) scores[e0 + eg*4 + j] = sp[j];
  }
  // fused edge_attr column-sum partials (for mean_attr)
  if (tid < 128){
    float s = 0.f;
    for (int e = 0; e < 64; ++e) s += ea[e*130 + tid];
    atomicAdd(&asum_mid[(blockIdx.x & 63)*DD + tid], s);
  }
}

// ---------------- me = (col_sum/E) @ W_edge ----------------
__global__ __launch_bounds__(128)
void k_me(const float* __restrict__ asum_mid, const float* __restrict__ W_edge,
          float* __restrict__ me)
{
  __shared__ float mean[128];
  const int d = threadIdx.x;
  float s = 0.f;
  for (int r = 0; r < 64; ++r) s += asum_mid[r*DD + d];
  mean[d] = s / (float)E_EDGES;
  __syncthreads();
  float acc = 0.f;
  for (int k = 0; k < 128; ++k) acc += mean[k] * W_edge[k*DD + d];
  me[d] = acc;
}

// ---------------- in-degree histogram ----------------
__global__ __launch_bounds__(256)
void k_hist(const int* __restrict__ ei, int* __restrict__ indeg)
{
  int e = blockIdx.x*256 + threadIdx.x;
  if (e < E_EDGES) atomicAdd(&indeg[ei[E_EDGES + e]], 1);
}

// ---------------- single-block exclusive scan (N=50000) ----------------
#define SCAN_CH 49
__global__ __launch_bounds__(1024)
void k_scan(const int* __restrict__ indeg, int* __restrict__ off)
{
  __shared__ int sA[1024], sB[1024];
  const int tid = threadIdx.x;
  const int base = tid * SCAN_CH;
  int s = 0;
  for (int i = 0; i < SCAN_CH; ++i){
    int id = base + i;
    if (id < N_NODES) s += indeg[id];
  }
  sA[tid] = s;
  __syncthreads();
  int* src = sA; int* dst = sB;
  for (int d = 1; d < 1024; d <<= 1){
    int v = src[tid] + (tid >= d ? src[tid-d] : 0);
    dst[tid] = v;
    __syncthreads();
    int* t = src; src = dst; dst = t;
  }
  int run = (tid == 0) ? 0 : src[tid-1];
  for (int i = 0; i < SCAN_CH; ++i){
    int id = base + i;
    if (id < N_NODES){ off[id] = run; run += indeg[id]; }
  }
  if (tid == 1023) off[N_NODES] = run;
}

// ---------------- scatter edges into CSR slots ----------------
__global__ __launch_bounds__(256)
void k_scatter(const int* __restrict__ ei, const float* __restrict__ scores,
               const int* __restrict__ off, int* __restrict__ pos,
               int* __restrict__ src_sorted, float* __restrict__ score_sorted)
{
  int e = blockIdx.x*256 + threadIdx.x;
  if (e >= E_EDGES) return;
  int d = ei[E_EDGES + e];
  int p = atomicAdd(&pos[d], 1);
  int slot = off[d] + p;
  src_sorted[slot] = ei[e];
  score_sorted[slot] = scores[e];
}

// ------- per-node softmax-aggregate (one wave/node) + pooled atomic add -------
__global__ __launch_bounds__(256)
void k_aggregate(const int* __restrict__ off, const int* __restrict__ src_sorted,
                 const float* __restrict__ score_sorted, const float* __restrict__ xl,
                 const float* __restrict__ xr, const float* __restrict__ me,
                 const float* __restrict__ att, const float* __restrict__ conv_bias,
                 const int* __restrict__ batch_vec,
                 float* __restrict__ gsum, float* __restrict__ gcnt)
{
  const int tid = threadIdx.x, lane = tid & 63, wid = tid >> 6;
  const int i = blockIdx.x*4 + wid;   // 12500*4 == N exactly
  float2 xli = *(const float2*)&xl[i*DD + lane*2];
  float2 xri = *(const float2*)&xr[i*DD + lane*2];
  float2 mev = *(const float2*)&me[lane*2];
  float2 attv = *(const float2*)&att[lane*2];
  float v0 = xli.x + xri.x + mev.x;
  float v1 = xli.y + xri.y + mev.y;
  float s_self = wsum(lrelu(v0)*attv.x + lrelu(v1)*attv.y);
  const int o0 = off[i], o1 = off[i+1];
  const int deg = o1 - o0;
  float m = s_self;
  for (int b = 0; b < deg; b += 64){
    int j = b + lane;
    float sc = (j < deg) ? score_sorted[o0 + j] : -INFINITY;
    m = fmaxf(m, sc);
  }
  m = wmax(m);
  float wse = expf(s_self - m);
  float den = wse;
  float a0 = wse * xli.x, a1 = wse * xli.y;
  for (int j = 0; j < deg; ++j){
    float sc = score_sorted[o0 + j];
    int s = src_sorted[o0 + j];
    float w = expf(sc - m);
    den += w;
    float2 xs = *(const float2*)&xl[s*DD + lane*2];
    a0 = fmaf(w, xs.x, a0);
    a1 = fmaf(w, xs.y, a1);
  }
  float inv = 1.0f / (den + 1e-16f);
  float2 cb2 = *(const float2*)&conv_bias[lane*2];
  float h0 = a0*inv + cb2.x;
  float h1 = a1*inv + cb2.y;
  int b = batch_vec[i];
  atomicAdd(&gsum[b*DD + lane*2],     h0);
  atomicAdd(&gsum[b*DD + lane*2 + 1], h1);
  if (lane == 0) atomicAdd(&gcnt[b], 1.0f);
}

// ---------------- pool-divide + adapter + layernorm ----------------
__global__ __launch_bounds__(128)
void k_pool(const float* __restrict__ gsum, const float* __restrict__ gcnt,
            const float* __restrict__ aW, const float* __restrict__ ab,
            const float* __restrict__ ng, const float* __restrict__ nb,
            float* __restrict__ g_ln)
{
  __shared__ float row[128];
  __shared__ float red[128];
  const int g = blockIdx.x, d = threadIdx.x;
  float denom = fmaxf(gcnt[g], 1.0f);
  row[d] = gsum[g*DD + d] / denom;
  __syncthreads();
  double accd = (double)ab[d];
  for (int k = 0; k < 128; ++k) accd += (double)row[k] * (double)aW[k*DD + d];
  float a = (float)accd;
  red[d] = a; __syncthreads();
  for (int s = 64; s > 0; s >>= 1){ if (d < s) red[d] += red[d+s]; __syncthreads(); }
  float mean = red[0] / 128.f; __syncthreads();
  float c = a - mean;
  red[d] = c*c; __syncthreads();
  for (int s = 64; s > 0; s >>= 1){ if (d < s) red[d] += red[d+s]; __syncthreads(); }
  float var = red[0] / 128.f; __syncthreads();
  float inv = (float)(1.0 / sqrt((double)var + (double)LN_EPS));
  g_ln[g*DD + d] = c * inv * ng[d] + nb[d];
}

// ---------------- residual VQ (Q=3, K=512) ----------------
__global__ __launch_bounds__(256)
void k_rvq(const float* __restrict__ g_ln, const float* __restrict__ codebooks,
           float* __restrict__ ind_out, int* __restrict__ idx_i,
           float* __restrict__ accs)
{
  __shared__ __align__(16) float r_lds[128];
  __shared__ float red[128];
  __shared__ double bd[64];
  __shared__ int bi[64];
  __shared__ int chosen;
  const int g = blockIdx.x, tid = threadIdx.x;
  if (tid < 128) r_lds[tid] = g_ln[g*DD + tid];
  __syncthreads();
  const int cl = tid >> 2, dq = tid & 3;
  for (int q = 0; q < Q_QUANT; ++q){
    const float* cb = codebooks + (size_t)q * K_CODES * DD;
    double bestd = 1e300; int besti = 1 << 30;
    for (int r = 0; r < 8; ++r){
      int c = r*64 + cl;
      double rc = 0.0, cc = 0.0;
      const float4* cp = (const float4*)&cb[c*DD + dq*32];
      const float4* rp = (const float4*)&r_lds[dq*32];
#pragma unroll
      for (int i = 0; i < 8; ++i){
        float4 cv = cp[i]; float4 rv = rp[i];
        rc += (double)cv.x*rv.x + (double)cv.y*rv.y + (double)cv.z*rv.z + (double)cv.w*rv.w;
        cc += (double)cv.x*cv.x + (double)cv.y*cv.y + (double)cv.z*cv.z + (double)cv.w*cv.w;
      }
      rc += __shfl_xor(rc, 1); rc += __shfl_xor(rc, 2);
      cc += __shfl_xor(cc, 1); cc += __shfl_xor(cc, 2);
      if (dq == 0){
        double d2 = cc - 2.0*rc;
        if (d2 < bestd || (d2 == bestd && c < besti)){ bestd = d2; besti = c; }
      }
    }
    if (dq == 0){ bd[cl] = bestd; bi[cl] = besti; }
    __syncthreads();
    if (tid < 64){
      double d2 = bd[tid]; int ii = bi[tid];
#pragma unroll
      for (int m = 1; m < 64; m <<= 1){
        double od = __shfl_xor(d2, m); int oi = __shfl_xor(ii, m);
        if (od < d2 || (od == d2 && oi < ii)){ d2 = od; ii = oi; }
      }
      if (tid == 0) chosen = ii;
    }
    __syncthreads();
    const int idx = chosen;
    if (tid == 0){
      ind_out[g*Q_QUANT + q] = (float)idx;
      idx_i[g*Q_QUANT + q] = idx;
    }
    if (tid < 128){
      float cd = cb[idx*DD + tid];
      float diff = cd - r_lds[tid];
      red[tid] = diff * diff;
      r_lds[tid] -= cd;
    }
    __syncthreads();
    for (int s = 64; s > 0; s >>= 1){ if (tid < s) red[tid] += red[tid+s]; __syncthreads(); }
    if (tid == 0) atomicAdd(&accs[q], red[0]);
    __syncthreads();
  }
  if (tid < 128) red[tid] = r_lds[tid]*r_lds[tid];
  __syncthreads();
  for (int s = 64; s > 0; s >>= 1){ if (tid < s) red[tid] += red[tid+s]; __syncthreads(); }
  if (tid == 0) atomicAdd(&accs[3], red[0]);
}

// ---------------- tokens: LN(code @ out_W + out_b) ----------------
__global__ __launch_bounds__(256)
void k_tokens(const float* __restrict__ codebooks, const int* __restrict__ idx_i,
              const float* __restrict__ out_W, const float* __restrict__ out_b,
              const float* __restrict__ og, const float* __restrict__ ob,
              float* __restrict__ tokens)
{
  __shared__ __align__(16) float c_lds[128];
  __shared__ float red[256];
  const int blk = blockIdx.x;
  const int g = blk / 3, q = blk % 3;
  const int tid = threadIdx.x;
  const int idx = idx_i[g*Q_QUANT + q];
  if (tid < 128) c_lds[tid] = codebooks[((size_t)q*K_CODES + idx)*DD + tid];
  __syncthreads();
  double v0 = (double)out_b[tid];
  double v1 = (double)out_b[tid + 256];
  for (int k = 0; k < 128; ++k){
    double ck = (double)c_lds[k];
    v0 += ck * (double)out_W[k*FD_OUT + tid];
    v1 += ck * (double)out_W[k*FD_OUT + tid + 256];
  }
  float f0 = (float)v0, f1 = (float)v1;
  red[tid] = f0 + f1; __syncthreads();
  for (int s = 128; s > 0; s >>= 1){ if (tid < s) red[tid] += red[tid+s]; __syncthreads(); }
  float mean = red[0] / 512.f; __syncthreads();
  float d0 = f0 - mean, d1 = f1 - mean;
  red[tid] = d0*d0 + d1*d1; __syncthreads();
  for (int s = 128; s > 0; s >>= 1){ if (tid < s) red[tid] += red[tid+s]; __syncthreads(); }
  float var = red[0] / 512.f; __syncthreads();
  float inv = (float)(1.0 / sqrt((double)var + (double)LN_EPS));
  tokens[(size_t)blk*FD_OUT + tid]       = d0*inv*og[tid] + ob[tid];
  tokens[(size_t)blk*FD_OUT + tid + 256] = d1*inv*og[tid+256] + ob[tid+256];
}

// ---------------- loss ----------------
__global__ void k_loss(const float* __restrict__ accs, float* __restrict__ out)
{
  float commit = (accs[0] + accs[1] + accs[2]) / (3.0f * G_GRAPHS * DD);
  float resid  = accs[3] / ((float)G_GRAPHS * DD);
  out[0] = commit + resid;
}

extern "C" void kernel_launch(void* const* d_in, const int* in_sizes, int n_in,
                              void* d_out, int out_size, void* d_ws, size_t ws_size,
                              hipStream_t stream)
{
  (void)in_sizes; (void)n_in; (void)out_size; (void)ws_size;
  const float* x         = (const float*)d_in[0];
  const int*   ei        = (const int*)d_in[1];
  const float* edge_attr = (const float*)d_in[2];
  const int*   batch_vec = (const int*)d_in[3];
  const float* W_l       = (const float*)d_in[4];
  const float* b_l       = (const float*)d_in[5];
  const float* W_r       = (const float*)d_in[6];
  const float* b_r       = (const float*)d_in[7];
  const float* W_edge    = (const float*)d_in[8];
  const float* att       = (const float*)d_in[9];
  const float* conv_bias = (const float*)d_in[10];
  const float* aW        = (const float*)d_in[11];
  const float* ab        = (const float*)d_in[12];
  const float* ng        = (const float*)d_in[13];
  const float* nb        = (const float*)d_in[14];
  const float* codebooks = (const float*)d_in[15];
  const float* out_W     = (const float*)d_in[16];
  const float* out_b     = (const float*)d_in[17];
  const float* og        = (const float*)d_in[18];
  const float* ob        = (const float*)d_in[19];
  float* outf = (float*)d_out;

  char* w = (char*)d_ws;
  size_t o = 0;
  auto nxt = [&](size_t bytes)->void*{
    void* p = w + o;
    o += (bytes + 511) & ~(size_t)511;
    return p;
  };
  float* xl           = (float*)nxt((size_t)N_NODES*DD*4);
  float* xr           = (float*)nxt((size_t)N_NODES*DD*4);
  float* scores       = (float*)nxt((size_t)E_EDGES*4);
  int*   src_sorted   = (int*)  nxt((size_t)E_EDGES*4);
  float* score_sorted = (float*)nxt((size_t)E_EDGES*4);
  int*   indeg        = (int*)  nxt((size_t)N_NODES*4);
  int*   off          = (int*)  nxt((size_t)(N_NODES+1)*4);
  int*   pos          = (int*)  nxt((size_t)N_NODES*4);
  float* asum_mid     = (float*)nxt((size_t)64*DD*4);
  float* me           = (float*)nxt((size_t)DD*4);
  float* gsum         = (float*)nxt((size_t)G_GRAPHS*DD*4);
  float* gcnt         = (float*)nxt((size_t)G_GRAPHS*4);
  float* g_ln         = (float*)nxt((size_t)G_GRAPHS*DD*4);
  int*   idx_i        = (int*)  nxt((size_t)G_GRAPHS*Q_QUANT*4);
  float* accs         = (float*)nxt(16);

  hipMemsetAsync(indeg,    0, (size_t)N_NODES*4,     stream);
  hipMemsetAsync(pos,      0, (size_t)N_NODES*4,     stream);
  hipMemsetAsync(asum_mid, 0, (size_t)64*DD*4,       stream);
  hipMemsetAsync(gsum,     0, (size_t)G_GRAPHS*DD*4, stream);
  hipMemsetAsync(gcnt,     0, (size_t)G_GRAPHS*4,    stream);
  hipMemsetAsync(accs,     0, 16,                    stream);

  k_xform<<<dim3((N_NODES+63)/64), dim3(256), 0, stream>>>(x, W_l, b_l, xl, N_NODES);
  k_xform<<<dim3((N_NODES+63)/64), dim3(256), 0, stream>>>(x, W_r, b_r, xr, N_NODES);
  k_hist<<<dim3((E_EDGES+255)/256), dim3(256), 0, stream>>>(ei, indeg);
  k_scan<<<dim3(1), dim3(1024), 0, stream>>>(indeg, off);
  k_edge<<<dim3(E_EDGES/64), dim3(256), 0, stream>>>(edge_attr, W_edge, ei, xl, xr, att,
                                                     scores, asum_mid);
  k_me<<<dim3(1), dim3(128), 0, stream>>>(asum_mid, W_edge, me);
  k_scatter<<<dim3((E_EDGES+255)/256), dim3(256), 0, stream>>>(ei, scores, off, pos,
                                                               src_sorted, score_sorted);
  k_aggregate<<<dim3(N_NODES/4), dim3(256), 0, stream>>>(off, src_sorted, score_sorted,
                                                         xl, xr, me, att, conv_bias,
                                                         batch_vec, gsum, gcnt);
  k_pool<<<dim3(G_GRAPHS), dim3(128), 0, stream>>>(gsum, gcnt, aW, ab, ng, nb, g_ln);
  k_rvq<<<dim3(G_GRAPHS), dim3(256), 0, stream>>>(g_ln, codebooks,
                                                  outf + (size_t)G_GRAPHS*Q_QUANT*FD_OUT,
                                                  idx_i, accs);
  k_tokens<<<dim3(G_GRAPHS*Q_QUANT), dim3(256), 0, stream>>>(codebooks, idx_i, out_W, out_b,
                                                             og, ob, outf);
  k_loss<<<dim3(1), dim3(1), 0, stream>>>(accs,
                                          outf + (size_t)G_GRAPHS*Q_QUANT*FD_OUT
                                               + (size_t)G_GRAPHS*Q_QUANT);
}

// Round 2
// 746.194 us; speedup vs baseline: 1.1437x; 1.1437x over previous
//
#include <hip/hip_runtime.h>
#include <math.h>

#define N_NODES 50000
#define E_EDGES 600000
#define DD 128
#define G_GRAPHS 512
#define K_CODES 512
#define Q_QUANT 3
#define FD_OUT 512
#define NEG_SLOPE 0.2f
#define LN_EPS 1e-5f

static __device__ __forceinline__ float lrelu(float v){ return v > 0.f ? v : NEG_SLOPE*v; }
static __device__ __forceinline__ float f4c(float4 v, int k){
  return k==0?v.x:(k==1?v.y:(k==2?v.z:v.w));
}
static __device__ __forceinline__ float wsum(float v){
#pragma unroll
  for (int m = 1; m < 64; m <<= 1) v += __shfl_xor(v, m);
  return v;
}
static __device__ __forceinline__ float wmax(float v){
#pragma unroll
  for (int m = 1; m < 64; m <<= 1) v = fmaxf(v, __shfl_xor(v, m));
  return v;
}

#define EA_LD 132   // row pad: 132 floats = 528B = 33*16B (keeps b128 alignment, shifts banks)

// ---------------- xl/xr transform: out[n][128] = x @ W + b ----------------
__global__ __launch_bounds__(256)
void k_xform(const float* __restrict__ x, const float* __restrict__ W,
             const float* __restrict__ bias, float* __restrict__ out, int n)
{
  __shared__ __align__(16) float xt[64*EA_LD];
  __shared__ __align__(16) float Wt[32*128];
  const int tid = threadIdx.x;
  const int r0 = blockIdx.x * 64;
  {
    const int q = tid & 63, eb = tid >> 6;
#pragma unroll
    for (int i = 0; i < 16; ++i){
      int e = eb + 4*i;
      int row = r0 + e;
      float2 v = make_float2(0.f, 0.f);
      if (row < n) v = *(const float2*)&x[row*DD + q*2];
      *(float2*)&xt[e*EA_LD + q*2] = v;
    }
  }
  const int eg = tid >> 4;   // row group (16 groups of 4 rows)
  const int cg = tid & 15;   // col group: cols cg*4..+3 and 64+cg*4..+3
  float4 acc0[4], acc1[4];
#pragma unroll
  for (int j = 0; j < 4; ++j){ acc0[j] = make_float4(0,0,0,0); acc1[j] = make_float4(0,0,0,0); }

  for (int kq = 0; kq < 4; ++kq){
    __syncthreads();
    {
      const int c4 = tid & 31, kb = tid >> 5;
#pragma unroll
      for (int i = 0; i < 4; ++i){
        int kk = kb + 8*i;
        *(float4*)&Wt[kk*128 + c4*4] = *(const float4*)&W[(kq*32+kk)*DD + c4*4];
      }
    }
    __syncthreads();
    const int kb2 = kq*32;
#pragma unroll
    for (int k4 = 0; k4 < 8; ++k4){
      float4 aa[4];
#pragma unroll
      for (int j = 0; j < 4; ++j)
        aa[j] = *(const float4*)&xt[(eg*4+j)*EA_LD + kb2 + k4*4];
#pragma unroll
      for (int kk = 0; kk < 4; ++kk){
        float4 b0 = *(const float4*)&Wt[(k4*4+kk)*128 + cg*4];
        float4 b1 = *(const float4*)&Wt[(k4*4+kk)*128 + 64 + cg*4];
#pragma unroll
        for (int j = 0; j < 4; ++j){
          float a = f4c(aa[j], kk);
          acc0[j].x = fmaf(a, b0.x, acc0[j].x);
          acc0[j].y = fmaf(a, b0.y, acc0[j].y);
          acc0[j].z = fmaf(a, b0.z, acc0[j].z);
          acc0[j].w = fmaf(a, b0.w, acc0[j].w);
          acc1[j].x = fmaf(a, b1.x, acc1[j].x);
          acc1[j].y = fmaf(a, b1.y, acc1[j].y);
          acc1[j].z = fmaf(a, b1.z, acc1[j].z);
          acc1[j].w = fmaf(a, b1.w, acc1[j].w);
        }
      }
    }
  }
  float4 bv0 = *(const float4*)&bias[cg*4];
  float4 bv1 = *(const float4*)&bias[64 + cg*4];
#pragma unroll
  for (int j = 0; j < 4; ++j){
    int row = r0 + eg*4 + j;
    if (row < n){
      float4 o0 = make_float4(acc0[j].x+bv0.x, acc0[j].y+bv0.y, acc0[j].z+bv0.z, acc0[j].w+bv0.w);
      float4 o1 = make_float4(acc1[j].x+bv1.x, acc1[j].y+bv1.y, acc1[j].z+bv1.z, acc1[j].w+bv1.w);
      *(float4*)&out[row*DD + cg*4]      = o0;
      *(float4*)&out[row*DD + 64 + cg*4] = o1;
    }
  }
}

// --------- per-edge score: e_emb = ea@W_edge (fused), score = lrelu(e).att ---------
// also: edge_attr column-sum partials (for mean_attr) and in-degree histogram (fused)
__global__ __launch_bounds__(256)
void k_edge(const float* __restrict__ edge_attr, const float* __restrict__ W_edge,
            const int* __restrict__ ei, const float* __restrict__ xl,
            const float* __restrict__ xr, const float* __restrict__ att,
            float* __restrict__ scores, float* __restrict__ asum_mid,
            int* __restrict__ indeg)
{
  __shared__ __align__(16) float ea[64*EA_LD];
  __shared__ __align__(16) float Wt[32*128];
  const int tid = threadIdx.x;
  const int e0 = blockIdx.x * 64;   // E divisible by 64
  {
    const int q = tid & 63, eb = tid >> 6;
#pragma unroll
    for (int i = 0; i < 16; ++i){
      int e = eb + 4*i;
      *(float2*)&ea[e*EA_LD + q*2] = *(const float2*)&edge_attr[(e0+e)*DD + q*2];
    }
  }
  const int eg = tid >> 4;
  const int cg = tid & 15;
  float4 acc0[4], acc1[4];
#pragma unroll
  for (int j = 0; j < 4; ++j){ acc0[j] = make_float4(0,0,0,0); acc1[j] = make_float4(0,0,0,0); }

  for (int kq = 0; kq < 4; ++kq){
    __syncthreads();
    {
      const int c4 = tid & 31, kb = tid >> 5;
#pragma unroll
      for (int i = 0; i < 4; ++i){
        int kk = kb + 8*i;
        *(float4*)&Wt[kk*128 + c4*4] = *(const float4*)&W_edge[(kq*32+kk)*DD + c4*4];
      }
    }
    __syncthreads();
    const int kb2 = kq*32;
#pragma unroll
    for (int k4 = 0; k4 < 8; ++k4){
      float4 aa[4];
#pragma unroll
      for (int j = 0; j < 4; ++j)
        aa[j] = *(const float4*)&ea[(eg*4+j)*EA_LD + kb2 + k4*4];
#pragma unroll
      for (int kk = 0; kk < 4; ++kk){
        float4 b0 = *(const float4*)&Wt[(k4*4+kk)*128 + cg*4];
        float4 b1 = *(const float4*)&Wt[(k4*4+kk)*128 + 64 + cg*4];
#pragma unroll
        for (int j = 0; j < 4; ++j){
          float a = f4c(aa[j], kk);
          acc0[j].x = fmaf(a, b0.x, acc0[j].x);
          acc0[j].y = fmaf(a, b0.y, acc0[j].y);
          acc0[j].z = fmaf(a, b0.z, acc0[j].z);
          acc0[j].w = fmaf(a, b0.w, acc0[j].w);
          acc1[j].x = fmaf(a, b1.x, acc1[j].x);
          acc1[j].y = fmaf(a, b1.y, acc1[j].y);
          acc1[j].z = fmaf(a, b1.z, acc1[j].z);
          acc1[j].w = fmaf(a, b1.w, acc1[j].w);
        }
      }
    }
  }
  // epilogue: add xl[src] + xr[dst], leaky-relu, dot with att, reduce over cg
  float4 at0 = *(const float4*)&att[cg*4];
  float4 at1 = *(const float4*)&att[64 + cg*4];
  float sp[4];
  int dsts[4];
#pragma unroll
  for (int j = 0; j < 4; ++j){
    int e = e0 + eg*4 + j;
    int s = ei[e];
    int d = ei[E_EDGES + e];
    dsts[j] = d;
    float4 xl0 = *(const float4*)&xl[s*DD + cg*4];
    float4 xl1 = *(const float4*)&xl[s*DD + 64 + cg*4];
    float4 xr0 = *(const float4*)&xr[d*DD + cg*4];
    float4 xr1 = *(const float4*)&xr[d*DD + 64 + cg*4];
    float p;
    p  = lrelu(acc0[j].x + xl0.x + xr0.x) * at0.x;
    p += lrelu(acc0[j].y + xl0.y + xr0.y) * at0.y;
    p += lrelu(acc0[j].z + xl0.z + xr0.z) * at0.z;
    p += lrelu(acc0[j].w + xl0.w + xr0.w) * at0.w;
    p += lrelu(acc1[j].x + xl1.x + xr1.x) * at1.x;
    p += lrelu(acc1[j].y + xl1.y + xr1.y) * at1.y;
    p += lrelu(acc1[j].z + xl1.z + xr1.z) * at1.z;
    p += lrelu(acc1[j].w + xl1.w + xr1.w) * at1.w;
    sp[j] = p;
  }
#pragma unroll
  for (int m = 1; m < 16; m <<= 1){
#pragma unroll
    for (int j = 0; j < 4; ++j) sp[j] += __shfl_xor(sp[j], m);
  }
  if (cg == 0){
#pragma unroll
    for (int j = 0; j < 4; ++j){
      scores[e0 + eg*4 + j] = sp[j];
      atomicAdd(&indeg[dsts[j]], 1);
    }
  }
  // fused edge_attr column-sum partials (for mean_attr)
  if (tid < 128){
    float s = 0.f;
    for (int e = 0; e < 64; ++e) s += ea[e*EA_LD + tid];
    atomicAdd(&asum_mid[(blockIdx.x & 63)*DD + tid], s);
  }
}

// ---------------- me = (col_sum/E) @ W_edge ----------------
__global__ __launch_bounds__(128)
void k_me(const float* __restrict__ asum_mid, const float* __restrict__ W_edge,
          float* __restrict__ me)
{
  __shared__ float mean[128];
  const int d = threadIdx.x;
  float s = 0.f;
  for (int r = 0; r < 64; ++r) s += asum_mid[r*DD + d];
  mean[d] = s / (float)E_EDGES;
  __syncthreads();
  float acc = 0.f;
  for (int k = 0; k < 128; ++k) acc += mean[k] * W_edge[k*DD + d];
  me[d] = acc;
}

// ---------------- single-block exclusive scan (N=50000) ----------------
#define SCAN_CH 49
__global__ __launch_bounds__(1024)
void k_scan(const int* __restrict__ indeg, int* __restrict__ off)
{
  __shared__ int sA[1024], sB[1024];
  const int tid = threadIdx.x;
  const int base = tid * SCAN_CH;
  int s = 0;
  for (int i = 0; i < SCAN_CH; ++i){
    int id = base + i;
    if (id < N_NODES) s += indeg[id];
  }
  sA[tid] = s;
  __syncthreads();
  int* src = sA; int* dst = sB;
  for (int d = 1; d < 1024; d <<= 1){
    int v = src[tid] + (tid >= d ? src[tid-d] : 0);
    dst[tid] = v;
    __syncthreads();
    int* t = src; src = dst; dst = t;
  }
  int run = (tid == 0) ? 0 : src[tid-1];
  for (int i = 0; i < SCAN_CH; ++i){
    int id = base + i;
    if (id < N_NODES){ off[id] = run; run += indeg[id]; }
  }
  if (tid == 1023) off[N_NODES] = run;
}

// ---------------- scatter edges into CSR slots (packed src+score records) ----------------
__global__ __launch_bounds__(256)
void k_scatter(const int* __restrict__ ei, const float* __restrict__ scores,
               const int* __restrict__ off, int* __restrict__ pos,
               uint2* __restrict__ rec)
{
  int e = blockIdx.x*256 + threadIdx.x;
  if (e >= E_EDGES) return;
  int d = ei[E_EDGES + e];
  int p = atomicAdd(&pos[d], 1);
  uint2 r;
  r.x = (unsigned)ei[e];
  r.y = __float_as_uint(scores[e]);
  rec[off[d] + p] = r;
}

// ------- per-node softmax-aggregate (one wave/node) + pooled block-reduced atomic add -------
__global__ __launch_bounds__(256)
void k_aggregate(const int* __restrict__ off, const uint2* __restrict__ rec,
                 const float* __restrict__ xl, const float* __restrict__ xr,
                 const float* __restrict__ me, const float* __restrict__ att,
                 const float* __restrict__ conv_bias, const int* __restrict__ batch_vec,
                 float* __restrict__ gsum, float* __restrict__ gcnt)
{
  __shared__ float hshare[4][128];
  __shared__ int bsh[4];
  const int tid = threadIdx.x, lane = tid & 63, wid = tid >> 6;
  const int i = blockIdx.x*4 + wid;   // 12500*4 == N exactly
  float2 xli = *(const float2*)&xl[i*DD + lane*2];
  float2 xri = *(const float2*)&xr[i*DD + lane*2];
  float2 mev = *(const float2*)&me[lane*2];
  float2 attv = *(const float2*)&att[lane*2];
  float v0 = xli.x + xri.x + mev.x;
  float v1 = xli.y + xri.y + mev.y;
  float s_self = wsum(lrelu(v0)*attv.x + lrelu(v1)*attv.y);
  const int o0 = off[i], o1 = off[i+1];
  const int deg = o1 - o0;
  // pass 1: max (keep first chunk's records in registers)
  uint2 myrec = make_uint2(0u, __float_as_uint(-INFINITY));
  float m = s_self;
  if (lane < deg) myrec = rec[o0 + lane];
  m = fmaxf(m, __uint_as_float(myrec.y));
  for (int b = 64; b < deg; b += 64){
    int j = b + lane;
    if (j < deg) m = fmaxf(m, __uint_as_float(rec[o0 + j].y));
  }
  m = wmax(m);
  // pass 2
  float wse = __expf(s_self - m);
  float den = wse;
  float a0 = wse * xli.x, a1 = wse * xli.y;
  if (deg <= 64){
    float msc = __uint_as_float(myrec.y);
    int msrc = (int)myrec.x;
#pragma unroll 2
    for (int j = 0; j < deg; ++j){
      float sc = __shfl(msc, j);
      int s = __shfl(msrc, j);
      float w = __expf(sc - m);
      den += w;
      float2 xs = *(const float2*)&xl[s*DD + lane*2];
      a0 = fmaf(w, xs.x, a0);
      a1 = fmaf(w, xs.y, a1);
    }
  } else {
#pragma unroll 2
    for (int j = 0; j < deg; ++j){
      uint2 r = rec[o0 + j];
      float w = __expf(__uint_as_float(r.y) - m);
      den += w;
      float2 xs = *(const float2*)&xl[(int)r.x*DD + lane*2];
      a0 = fmaf(w, xs.x, a0);
      a1 = fmaf(w, xs.y, a1);
    }
  }
  float inv = 1.0f / (den + 1e-16f);
  float2 cb2 = *(const float2*)&conv_bias[lane*2];
  float h0 = a0*inv + cb2.x;
  float h1 = a1*inv + cb2.y;
  int b = batch_vec[i];
  hshare[wid][lane*2]     = h0;
  hshare[wid][lane*2 + 1] = h1;
  if (lane == 0) bsh[wid] = b;
  __syncthreads();
  bool uni = (bsh[0]==bsh[1]) && (bsh[1]==bsh[2]) && (bsh[2]==bsh[3]);
  if (uni){
    if (wid == 0){
      float s0 = hshare[0][lane*2] + hshare[1][lane*2] + hshare[2][lane*2] + hshare[3][lane*2];
      float s1 = hshare[0][lane*2+1] + hshare[1][lane*2+1] + hshare[2][lane*2+1] + hshare[3][lane*2+1];
      atomicAdd(&gsum[b*DD + lane*2],     s0);
      atomicAdd(&gsum[b*DD + lane*2 + 1], s1);
      if (lane == 0) atomicAdd(&gcnt[b], 4.0f);
    }
  } else {
    atomicAdd(&gsum[b*DD + lane*2],     h0);
    atomicAdd(&gsum[b*DD + lane*2 + 1], h1);
    if (lane == 0) atomicAdd(&gcnt[b], 1.0f);
  }
}

// ---------------- pool-divide + adapter + layernorm ----------------
__global__ __launch_bounds__(128)
void k_pool(const float* __restrict__ gsum, const float* __restrict__ gcnt,
            const float* __restrict__ aW, const float* __restrict__ ab,
            const float* __restrict__ ng, const float* __restrict__ nb,
            float* __restrict__ g_ln)
{
  __shared__ float row[128];
  __shared__ float red[128];
  const int g = blockIdx.x, d = threadIdx.x;
  float denom = fmaxf(gcnt[g], 1.0f);
  row[d] = gsum[g*DD + d] / denom;
  __syncthreads();
  double accd = (double)ab[d];
  for (int k = 0; k < 128; ++k) accd += (double)row[k] * (double)aW[k*DD + d];
  float a = (float)accd;
  red[d] = a; __syncthreads();
  for (int s = 64; s > 0; s >>= 1){ if (d < s) red[d] += red[d+s]; __syncthreads(); }
  float mean = red[0] / 128.f; __syncthreads();
  float c = a - mean;
  red[d] = c*c; __syncthreads();
  for (int s = 64; s > 0; s >>= 1){ if (d < s) red[d] += red[d+s]; __syncthreads(); }
  float var = red[0] / 128.f; __syncthreads();
  float inv = (float)(1.0 / sqrt((double)var + (double)LN_EPS));
  g_ln[g*DD + d] = c * inv * ng[d] + nb[d];
}

// ---------------- residual VQ (Q=3, K=512) ----------------
__global__ __launch_bounds__(256)
void k_rvq(const float* __restrict__ g_ln, const float* __restrict__ codebooks,
           float* __restrict__ ind_out, int* __restrict__ idx_i,
           float* __restrict__ accs)
{
  __shared__ __align__(16) float r_lds[128];
  __shared__ float red[128];
  __shared__ double bd[64];
  __shared__ int bi[64];
  __shared__ int chosen;
  const int g = blockIdx.x, tid = threadIdx.x;
  if (tid < 128) r_lds[tid] = g_ln[g*DD + tid];
  __syncthreads();
  const int cl = tid >> 2, dq = tid & 3;
  for (int q = 0; q < Q_QUANT; ++q){
    const float* cb = codebooks + (size_t)q * K_CODES * DD;
    double bestd = 1e300; int besti = 1 << 30;
    for (int r = 0; r < 8; ++r){
      int c = r*64 + cl;
      double rc = 0.0, cc = 0.0;
      const float4* cp = (const float4*)&cb[c*DD + dq*32];
      const float4* rp = (const float4*)&r_lds[dq*32];
#pragma unroll
      for (int i = 0; i < 8; ++i){
        float4 cv = cp[i]; float4 rv = rp[i];
        rc += (double)cv.x*rv.x + (double)cv.y*rv.y + (double)cv.z*rv.z + (double)cv.w*rv.w;
        cc += (double)cv.x*cv.x + (double)cv.y*cv.y + (double)cv.z*cv.z + (double)cv.w*cv.w;
      }
      rc += __shfl_xor(rc, 1); rc += __shfl_xor(rc, 2);
      cc += __shfl_xor(cc, 1); cc += __shfl_xor(cc, 2);
      if (dq == 0){
        double d2 = cc - 2.0*rc;
        if (d2 < bestd || (d2 == bestd && c < besti)){ bestd = d2; besti = c; }
      }
    }
    if (dq == 0){ bd[cl] = bestd; bi[cl] = besti; }
    __syncthreads();
    if (tid < 64){
      double d2 = bd[tid]; int ii = bi[tid];
#pragma unroll
      for (int m = 1; m < 64; m <<= 1){
        double od = __shfl_xor(d2, m); int oi = __shfl_xor(ii, m);
        if (od < d2 || (od == d2 && oi < ii)){ d2 = od; ii = oi; }
      }
      if (tid == 0) chosen = ii;
    }
    __syncthreads();
    const int idx = chosen;
    if (tid == 0){
      ind_out[g*Q_QUANT + q] = (float)idx;
      idx_i[g*Q_QUANT + q] = idx;
    }
    if (tid < 128){
      float cd = cb[idx*DD + tid];
      float diff = cd - r_lds[tid];
      red[tid] = diff * diff;
      r_lds[tid] -= cd;
    }
    __syncthreads();
    for (int s = 64; s > 0; s >>= 1){ if (tid < s) red[tid] += red[tid+s]; __syncthreads(); }
    if (tid == 0) atomicAdd(&accs[q], red[0]);
    __syncthreads();
  }
  if (tid < 128) red[tid] = r_lds[tid]*r_lds[tid];
  __syncthreads();
  for (int s = 64; s > 0; s >>= 1){ if (tid < s) red[tid] += red[tid+s]; __syncthreads(); }
  if (tid == 0) atomicAdd(&accs[3], red[0]);
}

// ---------------- tokens: LN(code @ out_W + out_b) ----------------
__global__ __launch_bounds__(256)
void k_tokens(const float* __restrict__ codebooks, const int* __restrict__ idx_i,
              const float* __restrict__ out_W, const float* __restrict__ out_b,
              const float* __restrict__ og, const float* __restrict__ ob,
              float* __restrict__ tokens)
{
  __shared__ __align__(16) float c_lds[128];
  __shared__ float red[256];
  const int blk = blockIdx.x;
  const int g = blk / 3, q = blk % 3;
  const int tid = threadIdx.x;
  const int idx = idx_i[g*Q_QUANT + q];
  if (tid < 128) c_lds[tid] = codebooks[((size_t)q*K_CODES + idx)*DD + tid];
  __syncthreads();
  double v0 = (double)out_b[tid];
  double v1 = (double)out_b[tid + 256];
  for (int k = 0; k < 128; ++k){
    double ck = (double)c_lds[k];
    v0 += ck * (double)out_W[k*FD_OUT + tid];
    v1 += ck * (double)out_W[k*FD_OUT + tid + 256];
  }
  float f0 = (float)v0, f1 = (float)v1;
  red[tid] = f0 + f1; __syncthreads();
  for (int s = 128; s > 0; s >>= 1){ if (tid < s) red[tid] += red[tid+s]; __syncthreads(); }
  float mean = red[0] / 512.f; __syncthreads();
  float d0 = f0 - mean, d1 = f1 - mean;
  red[tid] = d0*d0 + d1*d1; __syncthreads();
  for (int s = 128; s > 0; s >>= 1){ if (tid < s) red[tid] += red[tid+s]; __syncthreads(); }
  float var = red[0] / 512.f; __syncthreads();
  float inv = (float)(1.0 / sqrt((double)var + (double)LN_EPS));
  tokens[(size_t)blk*FD_OUT + tid]       = d0*inv*og[tid] + ob[tid];
  tokens[(size_t)blk*FD_OUT + tid + 256] = d1*inv*og[tid+256] + ob[tid+256];
}

// ---------------- loss ----------------
__global__ void k_loss(const float* __restrict__ accs, float* __restrict__ out)
{
  float commit = (accs[0] + accs[1] + accs[2]) / (3.0f * G_GRAPHS * DD);
  float resid  = accs[3] / ((float)G_GRAPHS * DD);
  out[0] = commit + resid;
}

extern "C" void kernel_launch(void* const* d_in, const int* in_sizes, int n_in,
                              void* d_out, int out_size, void* d_ws, size_t ws_size,
                              hipStream_t stream)
{
  (void)in_sizes; (void)n_in; (void)out_size; (void)ws_size;
  const float* x         = (const float*)d_in[0];
  const int*   ei        = (const int*)d_in[1];
  const float* edge_attr = (const float*)d_in[2];
  const int*   batch_vec = (const int*)d_in[3];
  const float* W_l       = (const float*)d_in[4];
  const float* b_l       = (const float*)d_in[5];
  const float* W_r       = (const float*)d_in[6];
  const float* b_r       = (const float*)d_in[7];
  const float* W_edge    = (const float*)d_in[8];
  const float* att       = (const float*)d_in[9];
  const float* conv_bias = (const float*)d_in[10];
  const float* aW        = (const float*)d_in[11];
  const float* ab        = (const float*)d_in[12];
  const float* ng        = (const float*)d_in[13];
  const float* nb        = (const float*)d_in[14];
  const float* codebooks = (const float*)d_in[15];
  const float* out_W     = (const float*)d_in[16];
  const float* out_b     = (const float*)d_in[17];
  const float* og        = (const float*)d_in[18];
  const float* ob        = (const float*)d_in[19];
  float* outf = (float*)d_out;

  char* w = (char*)d_ws;
  size_t o = 0;
  auto nxt = [&](size_t bytes)->void*{
    void* p = w + o;
    o += (bytes + 511) & ~(size_t)511;
    return p;
  };
  float* xl       = (float*)nxt((size_t)N_NODES*DD*4);
  float* xr       = (float*)nxt((size_t)N_NODES*DD*4);
  float* scores   = (float*)nxt((size_t)E_EDGES*4);
  uint2* rec      = (uint2*)nxt((size_t)E_EDGES*8);
  int*   indeg    = (int*)  nxt((size_t)N_NODES*4);
  int*   off      = (int*)  nxt((size_t)(N_NODES+1)*4);
  int*   pos      = (int*)  nxt((size_t)N_NODES*4);
  float* asum_mid = (float*)nxt((size_t)64*DD*4);
  float* me       = (float*)nxt((size_t)DD*4);
  float* gsum     = (float*)nxt((size_t)G_GRAPHS*DD*4);
  float* gcnt     = (float*)nxt((size_t)G_GRAPHS*4);
  float* g_ln     = (float*)nxt((size_t)G_GRAPHS*DD*4);
  int*   idx_i    = (int*)  nxt((size_t)G_GRAPHS*Q_QUANT*4);
  float* accs     = (float*)nxt(16);

  hipMemsetAsync(indeg,    0, (size_t)N_NODES*4,     stream);
  hipMemsetAsync(pos,      0, (size_t)N_NODES*4,     stream);
  hipMemsetAsync(asum_mid, 0, (size_t)64*DD*4,       stream);
  hipMemsetAsync(gsum,     0, (size_t)G_GRAPHS*DD*4, stream);
  hipMemsetAsync(gcnt,     0, (size_t)G_GRAPHS*4,    stream);
  hipMemsetAsync(accs,     0, 16,                    stream);

  k_xform<<<dim3((N_NODES+63)/64), dim3(256), 0, stream>>>(x, W_l, b_l, xl, N_NODES);
  k_xform<<<dim3((N_NODES+63)/64), dim3(256), 0, stream>>>(x, W_r, b_r, xr, N_NODES);
  k_edge<<<dim3(E_EDGES/64), dim3(256), 0, stream>>>(edge_attr, W_edge, ei, xl, xr, att,
                                                     scores, asum_mid, indeg);
  k_scan<<<dim3(1), dim3(1024), 0, stream>>>(indeg, off);
  k_me<<<dim3(1), dim3(128), 0, stream>>>(asum_mid, W_edge, me);
  k_scatter<<<dim3((E_EDGES+255)/256), dim3(256), 0, stream>>>(ei, scores, off, pos, rec);
  k_aggregate<<<dim3(N_NODES/4), dim3(256), 0, stream>>>(off, rec, xl, xr, me, att,
                                                         conv_bias, batch_vec, gsum, gcnt);
  k_pool<<<dim3(G_GRAPHS), dim3(128), 0, stream>>>(gsum, gcnt, aW, ab, ng, nb, g_ln);
  k_rvq<<<dim3(G_GRAPHS), dim3(256), 0, stream>>>(g_ln, codebooks,
                                                  outf + (size_t)G_GRAPHS*Q_QUANT*FD_OUT,
                                                  idx_i, accs);
  k_tokens<<<dim3(G_GRAPHS*Q_QUANT), dim3(256), 0, stream>>>(codebooks, idx_i, out_W, out_b,
                                                             og, ob, outf);
  k_loss<<<dim3(1), dim3(1), 0, stream>>>(accs,
                                          outf + (size_t)G_GRAPHS*Q_QUANT*FD_OUT
                                               + (size_t)G_GRAPHS*Q_QUANT);
}

// Round 3
// 672.904 us; speedup vs baseline: 1.2682x; 1.1089x over previous
//
#include <hip/hip_runtime.h>
#include <math.h>

#define N_NODES 50000
#define E_EDGES 600000
#define DD 128
#define G_GRAPHS 512
#define K_CODES 512
#define Q_QUANT 3
#define FD_OUT 512
#define NEG_SLOPE 0.2f
#define LN_EPS 1e-5f

static __device__ __forceinline__ float lrelu(float v){ return v > 0.f ? v : NEG_SLOPE*v; }
static __device__ __forceinline__ float wsum(float v){
#pragma unroll
  for (int m = 1; m < 64; m <<= 1) v += __shfl_xor(v, m);
  return v;
}
static __device__ __forceinline__ float wmax(float v){
#pragma unroll
  for (int m = 1; m < 64; m <<= 1) v = fmaxf(v, __shfl_xor(v, m));
  return v;
}

#define EA_LD 130   // row pitch: 520B -> A-broadcast addrs land on distinct banks

// ---------------- xl/xr transform: out[n][128] = x @ W + b ----------------
// round-1 body (scalar A broadcast reads) + conflict-free B split (cg*4 / 64+cg*4)
__global__ __launch_bounds__(256)
void k_xform(const float* __restrict__ x, const float* __restrict__ W,
             const float* __restrict__ bias, float* __restrict__ out, int n)
{
  __shared__ __align__(16) float xt[64*EA_LD];
  __shared__ __align__(16) float Wt[32*128];
  const int tid = threadIdx.x;
  const int r0 = blockIdx.x * 64;
  {
    const int q = tid & 63, eb = tid >> 6;
#pragma unroll
    for (int i = 0; i < 16; ++i){
      int e = eb + 4*i;
      int row = r0 + e;
      float2 v = make_float2(0.f, 0.f);
      if (row < n) v = *(const float2*)&x[row*DD + q*2];
      *(float2*)&xt[e*EA_LD + q*2] = v;
    }
  }
  const int eg = tid >> 4;   // 16 row-groups of 4 rows
  const int cg = tid & 15;   // cols cg*4..+3 and 64+cg*4..+3
  float acc[4][8];
#pragma unroll
  for (int j = 0; j < 4; ++j)
#pragma unroll
    for (int u = 0; u < 8; ++u) acc[j][u] = 0.f;

  for (int kq = 0; kq < 4; ++kq){
    __syncthreads();
    {
      const int c4 = tid & 31, kb = tid >> 5;
#pragma unroll
      for (int i = 0; i < 4; ++i){
        int kk = kb + 8*i;
        *(float4*)&Wt[kk*128 + c4*4] = *(const float4*)&W[(kq*32+kk)*DD + c4*4];
      }
    }
    __syncthreads();
    const int kb2 = kq*32;
#pragma unroll 4
    for (int k = 0; k < 32; ++k){
      float aa[4];
#pragma unroll
      for (int j = 0; j < 4; ++j) aa[j] = xt[(eg*4+j)*EA_LD + kb2 + k];
      float bb[8];
      *(float4*)&bb[0] = *(const float4*)&Wt[k*128 + cg*4];
      *(float4*)&bb[4] = *(const float4*)&Wt[k*128 + 64 + cg*4];
#pragma unroll
      for (int j = 0; j < 4; ++j)
#pragma unroll
        for (int u = 0; u < 8; ++u) acc[j][u] = fmaf(aa[j], bb[u], acc[j][u]);
    }
  }
  float bv[8];
  *(float4*)&bv[0] = *(const float4*)&bias[cg*4];
  *(float4*)&bv[4] = *(const float4*)&bias[64 + cg*4];
#pragma unroll
  for (int j = 0; j < 4; ++j){
    int row = r0 + eg*4 + j;
    if (row < n){
      float o[8];
#pragma unroll
      for (int u = 0; u < 8; ++u) o[u] = acc[j][u] + bv[u];
      *(float4*)&out[row*DD + cg*4]      = *(const float4*)&o[0];
      *(float4*)&out[row*DD + 64 + cg*4] = *(const float4*)&o[4];
    }
  }
}

// --------- per-edge score: e_emb = ea@W_edge (fused), score = lrelu(e).att ---------
// fused: edge_attr column-sums (for mean_attr) and direct CSR scatter of (src,score)
__global__ __launch_bounds__(256)
void k_edge(const float* __restrict__ edge_attr, const float* __restrict__ W_edge,
            const int* __restrict__ ei, const float* __restrict__ xl,
            const float* __restrict__ xr, const float* __restrict__ att,
            const int* __restrict__ off, int* __restrict__ pos,
            uint2* __restrict__ rec, float* __restrict__ asum_mid)
{
  __shared__ __align__(16) float ea[64*EA_LD];
  __shared__ __align__(16) float Wt[32*128];
  const int tid = threadIdx.x;
  const int e0 = blockIdx.x * 64;   // E divisible by 64
  {
    const int q = tid & 63, eb = tid >> 6;
#pragma unroll
    for (int i = 0; i < 16; ++i){
      int e = eb + 4*i;
      *(float2*)&ea[e*EA_LD + q*2] = *(const float2*)&edge_attr[(e0+e)*DD + q*2];
    }
  }
  const int eg = tid >> 4;
  const int cg = tid & 15;
  float acc[4][8];
#pragma unroll
  for (int j = 0; j < 4; ++j)
#pragma unroll
    for (int u = 0; u < 8; ++u) acc[j][u] = 0.f;

  for (int kq = 0; kq < 4; ++kq){
    __syncthreads();
    {
      const int c4 = tid & 31, kb = tid >> 5;
#pragma unroll
      for (int i = 0; i < 4; ++i){
        int kk = kb + 8*i;
        *(float4*)&Wt[kk*128 + c4*4] = *(const float4*)&W_edge[(kq*32+kk)*DD + c4*4];
      }
    }
    __syncthreads();
    const int kb2 = kq*32;
#pragma unroll 4
    for (int k = 0; k < 32; ++k){
      float aa[4];
#pragma unroll
      for (int j = 0; j < 4; ++j) aa[j] = ea[(eg*4+j)*EA_LD + kb2 + k];
      float bb[8];
      *(float4*)&bb[0] = *(const float4*)&Wt[k*128 + cg*4];
      *(float4*)&bb[4] = *(const float4*)&Wt[k*128 + 64 + cg*4];
#pragma unroll
      for (int j = 0; j < 4; ++j)
#pragma unroll
        for (int u = 0; u < 8; ++u) acc[j][u] = fmaf(aa[j], bb[u], acc[j][u]);
    }
  }
  // epilogue: add xl[src] + xr[dst], leaky-relu, dot with att, reduce over cg
  float attv[8];
  *(float4*)&attv[0] = *(const float4*)&att[cg*4];
  *(float4*)&attv[4] = *(const float4*)&att[64 + cg*4];
  float sp[4];
  int dsts[4], srcs[4];
#pragma unroll
  for (int j = 0; j < 4; ++j){
    int e = e0 + eg*4 + j;
    int s = ei[e];
    int d = ei[E_EDGES + e];
    srcs[j] = s; dsts[j] = d;
    float xlv[8], xrv[8];
    *(float4*)&xlv[0] = *(const float4*)&xl[s*DD + cg*4];
    *(float4*)&xlv[4] = *(const float4*)&xl[s*DD + 64 + cg*4];
    *(float4*)&xrv[0] = *(const float4*)&xr[d*DD + cg*4];
    *(float4*)&xrv[4] = *(const float4*)&xr[d*DD + 64 + cg*4];
    float p = 0.f;
#pragma unroll
    for (int u = 0; u < 8; ++u){
      float vv = acc[j][u] + xlv[u] + xrv[u];
      p += lrelu(vv) * attv[u];
    }
    sp[j] = p;
  }
#pragma unroll
  for (int m = 1; m < 16; m <<= 1){
#pragma unroll
    for (int j = 0; j < 4; ++j) sp[j] += __shfl_xor(sp[j], m);
  }
  if (cg == 0){
#pragma unroll
    for (int j = 0; j < 4; ++j){
      int d = dsts[j];
      int p = atomicAdd(&pos[d], 1);
      uint2 r;
      r.x = (unsigned)srcs[j];
      r.y = __float_as_uint(sp[j]);
      rec[off[d] + p] = r;
    }
  }
  // fused edge_attr column-sum partials (for mean_attr)
  if (tid < 128){
    float s = 0.f;
    for (int e = 0; e < 64; ++e) s += ea[e*EA_LD + tid];
    atomicAdd(&asum_mid[(blockIdx.x & 63)*DD + tid], s);
  }
}

// ---------------- me = (col_sum/E) @ W_edge ----------------
__global__ __launch_bounds__(128)
void k_me(const float* __restrict__ asum_mid, const float* __restrict__ W_edge,
          float* __restrict__ me)
{
  __shared__ float mean[128];
  const int d = threadIdx.x;
  float s = 0.f;
  for (int r = 0; r < 64; ++r) s += asum_mid[r*DD + d];
  mean[d] = s / (float)E_EDGES;
  __syncthreads();
  float acc = 0.f;
  for (int k = 0; k < 128; ++k) acc += mean[k] * W_edge[k*DD + d];
  me[d] = acc;
}

// ---------------- in-degree histogram ----------------
__global__ __launch_bounds__(256)
void k_hist(const int* __restrict__ ei, int* __restrict__ indeg)
{
  int e = blockIdx.x*256 + threadIdx.x;
  if (e < E_EDGES) atomicAdd(&indeg[ei[E_EDGES + e]], 1);
}

// ---------------- single-block exclusive scan (N=50000) ----------------
#define SCAN_CH 49
__global__ __launch_bounds__(1024)
void k_scan(const int* __restrict__ indeg, int* __restrict__ off)
{
  __shared__ int sA[1024], sB[1024];
  const int tid = threadIdx.x;
  const int base = tid * SCAN_CH;
  int s = 0;
  for (int i = 0; i < SCAN_CH; ++i){
    int id = base + i;
    if (id < N_NODES) s += indeg[id];
  }
  sA[tid] = s;
  __syncthreads();
  int* src = sA; int* dst = sB;
  for (int d = 1; d < 1024; d <<= 1){
    int v = src[tid] + (tid >= d ? src[tid-d] : 0);
    dst[tid] = v;
    __syncthreads();
    int* t = src; src = dst; dst = t;
  }
  int run = (tid == 0) ? 0 : src[tid-1];
  for (int i = 0; i < SCAN_CH; ++i){
    int id = base + i;
    if (id < N_NODES){ off[id] = run; run += indeg[id]; }
  }
  if (tid == 1023) off[N_NODES] = run;
}

// ------- per-node softmax-aggregate (one wave/node) + pooled block-reduced atomic add -------
__global__ __launch_bounds__(256)
void k_aggregate(const int* __restrict__ off, const uint2* __restrict__ rec,
                 const float* __restrict__ xl, const float* __restrict__ xr,
                 const float* __restrict__ me, const float* __restrict__ att,
                 const float* __restrict__ conv_bias, const int* __restrict__ batch_vec,
                 float* __restrict__ gsum, float* __restrict__ gcnt)
{
  __shared__ float hshare[4][128];
  __shared__ int bsh[4];
  const int tid = threadIdx.x, lane = tid & 63, wid = tid >> 6;
  const int i = blockIdx.x*4 + wid;   // 12500*4 == N exactly
  float2 xli = *(const float2*)&xl[i*DD + lane*2];
  float2 xri = *(const float2*)&xr[i*DD + lane*2];
  float2 mev = *(const float2*)&me[lane*2];
  float2 attv = *(const float2*)&att[lane*2];
  float v0 = xli.x + xri.x + mev.x;
  float v1 = xli.y + xri.y + mev.y;
  float s_self = wsum(lrelu(v0)*attv.x + lrelu(v1)*attv.y);
  const int o0 = off[i], o1 = off[i+1];
  const int deg = o1 - o0;
  // pass 1: max (keep first chunk's records in registers)
  uint2 myrec = make_uint2(0u, __float_as_uint(-INFINITY));
  float m = s_self;
  if (lane < deg) myrec = rec[o0 + lane];
  m = fmaxf(m, __uint_as_float(myrec.y));
  for (int b = 64; b < deg; b += 64){
    int j = b + lane;
    if (j < deg) m = fmaxf(m, __uint_as_float(rec[o0 + j].y));
  }
  m = wmax(m);
  // pass 2
  float wse = __expf(s_self - m);
  float den = wse;
  float a0 = wse * xli.x, a1 = wse * xli.y;
  if (deg <= 64){
    float msc = __uint_as_float(myrec.y);
    int msrc = (int)myrec.x;
#pragma unroll 2
    for (int j = 0; j < deg; ++j){
      float sc = __shfl(msc, j);
      int s = __shfl(msrc, j);
      float w = __expf(sc - m);
      den += w;
      float2 xs = *(const float2*)&xl[s*DD + lane*2];
      a0 = fmaf(w, xs.x, a0);
      a1 = fmaf(w, xs.y, a1);
    }
  } else {
#pragma unroll 2
    for (int j = 0; j < deg; ++j){
      uint2 r = rec[o0 + j];
      float w = __expf(__uint_as_float(r.y) - m);
      den += w;
      float2 xs = *(const float2*)&xl[(int)r.x*DD + lane*2];
      a0 = fmaf(w, xs.x, a0);
      a1 = fmaf(w, xs.y, a1);
    }
  }
  float inv = 1.0f / (den + 1e-16f);
  float2 cb2 = *(const float2*)&conv_bias[lane*2];
  float h0 = a0*inv + cb2.x;
  float h1 = a1*inv + cb2.y;
  int b = batch_vec[i];
  hshare[wid][lane*2]     = h0;
  hshare[wid][lane*2 + 1] = h1;
  if (lane == 0) bsh[wid] = b;
  __syncthreads();
  bool uni = (bsh[0]==bsh[1]) && (bsh[1]==bsh[2]) && (bsh[2]==bsh[3]);
  if (uni){
    if (wid == 0){
      float s0 = hshare[0][lane*2] + hshare[1][lane*2] + hshare[2][lane*2] + hshare[3][lane*2];
      float s1 = hshare[0][lane*2+1] + hshare[1][lane*2+1] + hshare[2][lane*2+1] + hshare[3][lane*2+1];
      atomicAdd(&gsum[b*DD + lane*2],     s0);
      atomicAdd(&gsum[b*DD + lane*2 + 1], s1);
      if (lane == 0) atomicAdd(&gcnt[b], 4.0f);
    }
  } else {
    atomicAdd(&gsum[b*DD + lane*2],     h0);
    atomicAdd(&gsum[b*DD + lane*2 + 1], h1);
    if (lane == 0) atomicAdd(&gcnt[b], 1.0f);
  }
}

// ---------------- pool-divide + adapter + layernorm ----------------
__global__ __launch_bounds__(128)
void k_pool(const float* __restrict__ gsum, const float* __restrict__ gcnt,
            const float* __restrict__ aW, const float* __restrict__ ab,
            const float* __restrict__ ng, const float* __restrict__ nb,
            float* __restrict__ g_ln)
{
  __shared__ float row[128];
  __shared__ float red[128];
  const int g = blockIdx.x, d = threadIdx.x;
  float denom = fmaxf(gcnt[g], 1.0f);
  row[d] = gsum[g*DD + d] / denom;
  __syncthreads();
  double accd = (double)ab[d];
  for (int k = 0; k < 128; ++k) accd += (double)row[k] * (double)aW[k*DD + d];
  float a = (float)accd;
  red[d] = a; __syncthreads();
  for (int s = 64; s > 0; s >>= 1){ if (d < s) red[d] += red[d+s]; __syncthreads(); }
  float mean = red[0] / 128.f; __syncthreads();
  float c = a - mean;
  red[d] = c*c; __syncthreads();
  for (int s = 64; s > 0; s >>= 1){ if (d < s) red[d] += red[d+s]; __syncthreads(); }
  float var = red[0] / 128.f; __syncthreads();
  float inv = (float)(1.0 / sqrt((double)var + (double)LN_EPS));
  g_ln[g*DD + d] = c * inv * ng[d] + nb[d];
}

// ---------------- residual VQ (Q=3, K=512) ----------------
__global__ __launch_bounds__(256)
void k_rvq(const float* __restrict__ g_ln, const float* __restrict__ codebooks,
           float* __restrict__ ind_out, int* __restrict__ idx_i,
           float* __restrict__ accs)
{
  __shared__ __align__(16) float r_lds[128];
  __shared__ float red[128];
  __shared__ double bd[64];
  __shared__ int bi[64];
  __shared__ int chosen;
  const int g = blockIdx.x, tid = threadIdx.x;
  if (tid < 128) r_lds[tid] = g_ln[g*DD + tid];
  __syncthreads();
  const int cl = tid >> 2, dq = tid & 3;
  for (int q = 0; q < Q_QUANT; ++q){
    const float* cb = codebooks + (size_t)q * K_CODES * DD;
    double bestd = 1e300; int besti = 1 << 30;
    for (int r = 0; r < 8; ++r){
      int c = r*64 + cl;
      double rc = 0.0, cc = 0.0;
      const float4* cp = (const float4*)&cb[c*DD + dq*32];
      const float4* rp = (const float4*)&r_lds[dq*32];
#pragma unroll
      for (int i = 0; i < 8; ++i){
        float4 cv = cp[i]; float4 rv = rp[i];
        rc += (double)cv.x*rv.x + (double)cv.y*rv.y + (double)cv.z*rv.z + (double)cv.w*rv.w;
        cc += (double)cv.x*cv.x + (double)cv.y*cv.y + (double)cv.z*cv.z + (double)cv.w*cv.w;
      }
      rc += __shfl_xor(rc, 1); rc += __shfl_xor(rc, 2);
      cc += __shfl_xor(cc, 1); cc += __shfl_xor(cc, 2);
      if (dq == 0){
        double d2 = cc - 2.0*rc;
        if (d2 < bestd || (d2 == bestd && c < besti)){ bestd = d2; besti = c; }
      }
    }
    if (dq == 0){ bd[cl] = bestd; bi[cl] = besti; }
    __syncthreads();
    if (tid < 64){
      double d2 = bd[tid]; int ii = bi[tid];
#pragma unroll
      for (int m = 1; m < 64; m <<= 1){
        double od = __shfl_xor(d2, m); int oi = __shfl_xor(ii, m);
        if (od < d2 || (od == d2 && oi < ii)){ d2 = od; ii = oi; }
      }
      if (tid == 0) chosen = ii;
    }
    __syncthreads();
    const int idx = chosen;
    if (tid == 0){
      ind_out[g*Q_QUANT + q] = (float)idx;
      idx_i[g*Q_QUANT + q] = idx;
    }
    if (tid < 128){
      float cd = cb[idx*DD + tid];
      float diff = cd - r_lds[tid];
      red[tid] = diff * diff;
      r_lds[tid] -= cd;
    }
    __syncthreads();
    for (int s = 64; s > 0; s >>= 1){ if (tid < s) red[tid] += red[tid+s]; __syncthreads(); }
    if (tid == 0) atomicAdd(&accs[q], red[0]);
    __syncthreads();
  }
  if (tid < 128) red[tid] = r_lds[tid]*r_lds[tid];
  __syncthreads();
  for (int s = 64; s > 0; s >>= 1){ if (tid < s) red[tid] += red[tid+s]; __syncthreads(); }
  if (tid == 0) atomicAdd(&accs[3], red[0]);
}

// ---------------- tokens: LN(code @ out_W + out_b) ----------------
__global__ __launch_bounds__(256)
void k_tokens(const float* __restrict__ codebooks, const int* __restrict__ idx_i,
              const float* __restrict__ out_W, const float* __restrict__ out_b,
              const float* __restrict__ og, const float* __restrict__ ob,
              float* __restrict__ tokens)
{
  __shared__ __align__(16) float c_lds[128];
  __shared__ float red[256];
  const int blk = blockIdx.x;
  const int g = blk / 3, q = blk % 3;
  const int tid = threadIdx.x;
  const int idx = idx_i[g*Q_QUANT + q];
  if (tid < 128) c_lds[tid] = codebooks[((size_t)q*K_CODES + idx)*DD + tid];
  __syncthreads();
  double v0 = (double)out_b[tid];
  double v1 = (double)out_b[tid + 256];
  for (int k = 0; k < 128; ++k){
    double ck = (double)c_lds[k];
    v0 += ck * (double)out_W[k*FD_OUT + tid];
    v1 += ck * (double)out_W[k*FD_OUT + tid + 256];
  }
  float f0 = (float)v0, f1 = (float)v1;
  red[tid] = f0 + f1; __syncthreads();
  for (int s = 128; s > 0; s >>= 1){ if (tid < s) red[tid] += red[tid+s]; __syncthreads(); }
  float mean = red[0] / 512.f; __syncthreads();
  float d0 = f0 - mean, d1 = f1 - mean;
  red[tid] = d0*d0 + d1*d1; __syncthreads();
  for (int s = 128; s > 0; s >>= 1){ if (tid < s) red[tid] += red[tid+s]; __syncthreads(); }
  float var = red[0] / 512.f; __syncthreads();
  float inv = (float)(1.0 / sqrt((double)var + (double)LN_EPS));
  tokens[(size_t)blk*FD_OUT + tid]       = d0*inv*og[tid] + ob[tid];
  tokens[(size_t)blk*FD_OUT + tid + 256] = d1*inv*og[tid+256] + ob[tid+256];
}

// ---------------- loss ----------------
__global__ void k_loss(const float* __restrict__ accs, float* __restrict__ out)
{
  float commit = (accs[0] + accs[1] + accs[2]) / (3.0f * G_GRAPHS * DD);
  float resid  = accs[3] / ((float)G_GRAPHS * DD);
  out[0] = commit + resid;
}

extern "C" void kernel_launch(void* const* d_in, const int* in_sizes, int n_in,
                              void* d_out, int out_size, void* d_ws, size_t ws_size,
                              hipStream_t stream)
{
  (void)in_sizes; (void)n_in; (void)out_size; (void)ws_size;
  const float* x         = (const float*)d_in[0];
  const int*   ei        = (const int*)d_in[1];
  const float* edge_attr = (const float*)d_in[2];
  const int*   batch_vec = (const int*)d_in[3];
  const float* W_l       = (const float*)d_in[4];
  const float* b_l       = (const float*)d_in[5];
  const float* W_r       = (const float*)d_in[6];
  const float* b_r       = (const float*)d_in[7];
  const float* W_edge    = (const float*)d_in[8];
  const float* att       = (const float*)d_in[9];
  const float* conv_bias = (const float*)d_in[10];
  const float* aW        = (const float*)d_in[11];
  const float* ab        = (const float*)d_in[12];
  const float* ng        = (const float*)d_in[13];
  const float* nb        = (const float*)d_in[14];
  const float* codebooks = (const float*)d_in[15];
  const float* out_W     = (const float*)d_in[16];
  const float* out_b     = (const float*)d_in[17];
  const float* og        = (const float*)d_in[18];
  const float* ob        = (const float*)d_in[19];
  float* outf = (float*)d_out;

  char* w = (char*)d_ws;
  size_t o = 0;
  auto nxt = [&](size_t bytes)->void*{
    void* p = w + o;
    o += (bytes + 511) & ~(size_t)511;
    return p;
  };
  // --- zeroed buffers first (single memset over the span) ---
  int*   indeg    = (int*)  nxt((size_t)N_NODES*4);
  int*   pos      = (int*)  nxt((size_t)N_NODES*4);
  float* asum_mid = (float*)nxt((size_t)64*DD*4);
  float* gsum     = (float*)nxt((size_t)G_GRAPHS*DD*4);
  float* gcnt     = (float*)nxt((size_t)G_GRAPHS*4);
  float* accs     = (float*)nxt(16);
  const size_t zero_span = o;
  // --- non-zeroed ---
  int*   off      = (int*)  nxt((size_t)(N_NODES+1)*4);
  float* xl       = (float*)nxt((size_t)N_NODES*DD*4);
  float* xr       = (float*)nxt((size_t)N_NODES*DD*4);
  uint2* rec      = (uint2*)nxt((size_t)E_EDGES*8);
  float* me       = (float*)nxt((size_t)DD*4);
  float* g_ln     = (float*)nxt((size_t)G_GRAPHS*DD*4);
  int*   idx_i    = (int*)  nxt((size_t)G_GRAPHS*Q_QUANT*4);

  hipMemsetAsync(w, 0, zero_span, stream);

  k_hist<<<dim3((E_EDGES+255)/256), dim3(256), 0, stream>>>(ei, indeg);
  k_scan<<<dim3(1), dim3(1024), 0, stream>>>(indeg, off);
  k_xform<<<dim3((N_NODES+63)/64), dim3(256), 0, stream>>>(x, W_l, b_l, xl, N_NODES);
  k_xform<<<dim3((N_NODES+63)/64), dim3(256), 0, stream>>>(x, W_r, b_r, xr, N_NODES);
  k_edge<<<dim3(E_EDGES/64), dim3(256), 0, stream>>>(edge_attr, W_edge, ei, xl, xr, att,
                                                     off, pos, rec, asum_mid);
  k_me<<<dim3(1), dim3(128), 0, stream>>>(asum_mid, W_edge, me);
  k_aggregate<<<dim3(N_NODES/4), dim3(256), 0, stream>>>(off, rec, xl, xr, me, att,
                                                         conv_bias, batch_vec, gsum, gcnt);
  k_pool<<<dim3(G_GRAPHS), dim3(128), 0, stream>>>(gsum, gcnt, aW, ab, ng, nb, g_ln);
  k_rvq<<<dim3(G_GRAPHS), dim3(256), 0, stream>>>(g_ln, codebooks,
                                                  outf + (size_t)G_GRAPHS*Q_QUANT*FD_OUT,
                                                  idx_i, accs);
  k_tokens<<<dim3(G_GRAPHS*Q_QUANT), dim3(256), 0, stream>>>(codebooks, idx_i, out_W, out_b,
                                                             og, ob, outf);
  k_loss<<<dim3(1), dim3(1), 0, stream>>>(accs,
                                          outf + (size_t)G_GRAPHS*Q_QUANT*FD_OUT
                                               + (size_t)G_GRAPHS*Q_QUANT);
}

// Round 4
// 665.334 us; speedup vs baseline: 1.2827x; 1.0114x over previous
//
#include <hip/hip_runtime.h>
#include <math.h>

#define N_NODES 50000
#define E_EDGES 600000
#define DD 128
#define G_GRAPHS 512
#define K_CODES 512
#define Q_QUANT 3
#define FD_OUT 512
#define NEG_SLOPE 0.2f
#define LN_EPS 1e-5f

static __device__ __forceinline__ float lrelu(float v){ return v > 0.f ? v : NEG_SLOPE*v; }
static __device__ __forceinline__ float wsum(float v){
#pragma unroll
  for (int m = 1; m < 64; m <<= 1) v += __shfl_xor(v, m);
  return v;
}
static __device__ __forceinline__ float wmax(float v){
#pragma unroll
  for (int m = 1; m < 64; m <<= 1) v = fmaxf(v, __shfl_xor(v, m));
  return v;
}

#define EA_LD 130   // row pitch: 520B -> A-broadcast addrs land on distinct banks

// ---------------- fused transform: xl = x@W_l + b_l ; xr = x@W_r + b_r ----------------
// shared x tile + shared A-reads feed both accumulators (FMA:LDS doubled)
__global__ __launch_bounds__(256, 2)
void k_xform2(const float* __restrict__ x,
              const float* __restrict__ W_l, const float* __restrict__ b_l,
              const float* __restrict__ W_r, const float* __restrict__ b_r,
              float* __restrict__ xl, float* __restrict__ xr, int n)
{
  __shared__ __align__(16) float xt[64*EA_LD];
  __shared__ __align__(16) float WtL[32*128];
  __shared__ __align__(16) float WtR[32*128];
  const int tid = threadIdx.x;
  const int r0 = blockIdx.x * 64;
  const int c4 = tid & 31, kb = tid >> 5;
  // stage x tile + W quarter 0 (both), then one barrier
  {
    const int q = tid & 63, eb = tid >> 6;
#pragma unroll
    for (int i = 0; i < 16; ++i){
      int e = eb + 4*i;
      int row = r0 + e;
      float2 v = make_float2(0.f, 0.f);
      if (row < n) v = *(const float2*)&x[row*DD + q*2];
      *(float2*)&xt[e*EA_LD + q*2] = v;
    }
    float4 w0L[4], w0R[4];
#pragma unroll
    for (int i = 0; i < 4; ++i){
      w0L[i] = *(const float4*)&W_l[(kb + 8*i)*DD + c4*4];
      w0R[i] = *(const float4*)&W_r[(kb + 8*i)*DD + c4*4];
    }
#pragma unroll
    for (int i = 0; i < 4; ++i){
      *(float4*)&WtL[(kb + 8*i)*128 + c4*4] = w0L[i];
      *(float4*)&WtR[(kb + 8*i)*128 + c4*4] = w0R[i];
    }
  }
  __syncthreads();

  const int eg = tid >> 4;
  const int cg = tid & 15;
  float accL[4][8], accR[4][8];
#pragma unroll
  for (int j = 0; j < 4; ++j)
#pragma unroll
    for (int u = 0; u < 8; ++u){ accL[j][u] = 0.f; accR[j][u] = 0.f; }

  for (int kq = 0; kq < 4; ++kq){
    float4 wregL[4], wregR[4];
    if (kq < 3){
#pragma unroll
      for (int i = 0; i < 4; ++i){
        wregL[i] = *(const float4*)&W_l[((kq+1)*32 + kb + 8*i)*DD + c4*4];
        wregR[i] = *(const float4*)&W_r[((kq+1)*32 + kb + 8*i)*DD + c4*4];
      }
    }
    const int kb2 = kq*32;
    for (int kp = 0; kp < 16; ++kp){
      float2 aa[4];
#pragma unroll
      for (int j = 0; j < 4; ++j)
        aa[j] = *(const float2*)&xt[(eg*4+j)*EA_LD + kb2 + kp*2];
      float bL[16], bR[16];
      *(float4*)&bL[0]  = *(const float4*)&WtL[(kp*2)*128 + cg*4];
      *(float4*)&bL[4]  = *(const float4*)&WtL[(kp*2)*128 + 64 + cg*4];
      *(float4*)&bL[8]  = *(const float4*)&WtL[(kp*2+1)*128 + cg*4];
      *(float4*)&bL[12] = *(const float4*)&WtL[(kp*2+1)*128 + 64 + cg*4];
      *(float4*)&bR[0]  = *(const float4*)&WtR[(kp*2)*128 + cg*4];
      *(float4*)&bR[4]  = *(const float4*)&WtR[(kp*2)*128 + 64 + cg*4];
      *(float4*)&bR[8]  = *(const float4*)&WtR[(kp*2+1)*128 + cg*4];
      *(float4*)&bR[12] = *(const float4*)&WtR[(kp*2+1)*128 + 64 + cg*4];
#pragma unroll
      for (int j = 0; j < 4; ++j){
#pragma unroll
        for (int u = 0; u < 8; ++u) accL[j][u] = fmaf(aa[j].x, bL[u],   accL[j][u]);
#pragma unroll
        for (int u = 0; u < 8; ++u) accL[j][u] = fmaf(aa[j].y, bL[8+u], accL[j][u]);
#pragma unroll
        for (int u = 0; u < 8; ++u) accR[j][u] = fmaf(aa[j].x, bR[u],   accR[j][u]);
#pragma unroll
        for (int u = 0; u < 8; ++u) accR[j][u] = fmaf(aa[j].y, bR[8+u], accR[j][u]);
      }
    }
    if (kq < 3){
      __syncthreads();
#pragma unroll
      for (int i = 0; i < 4; ++i){
        *(float4*)&WtL[(kb + 8*i)*128 + c4*4] = wregL[i];
        *(float4*)&WtR[(kb + 8*i)*128 + c4*4] = wregR[i];
      }
      __syncthreads();
    }
  }
  float bvL[8], bvR[8];
  *(float4*)&bvL[0] = *(const float4*)&b_l[cg*4];
  *(float4*)&bvL[4] = *(const float4*)&b_l[64 + cg*4];
  *(float4*)&bvR[0] = *(const float4*)&b_r[cg*4];
  *(float4*)&bvR[4] = *(const float4*)&b_r[64 + cg*4];
#pragma unroll
  for (int j = 0; j < 4; ++j){
    int row = r0 + eg*4 + j;
    if (row < n){
      float oL[8], oR[8];
#pragma unroll
      for (int u = 0; u < 8; ++u){ oL[u] = accL[j][u] + bvL[u]; oR[u] = accR[j][u] + bvR[u]; }
      *(float4*)&xl[row*DD + cg*4]      = *(const float4*)&oL[0];
      *(float4*)&xl[row*DD + 64 + cg*4] = *(const float4*)&oL[4];
      *(float4*)&xr[row*DD + cg*4]      = *(const float4*)&oR[0];
      *(float4*)&xr[row*DD + 64 + cg*4] = *(const float4*)&oR[4];
    }
  }
}

// --------- per-edge score: e_emb = ea@W_edge (fused), score = lrelu(e).att ---------
// fused: edge_attr column-sums (for mean_attr) and direct CSR scatter of (src,score)
// k-pair inner loop + W register-prefetch pipeline
__global__ __launch_bounds__(256, 3)
void k_edge(const float* __restrict__ edge_attr, const float* __restrict__ W_edge,
            const int* __restrict__ ei, const float* __restrict__ xl,
            const float* __restrict__ xr, const float* __restrict__ att,
            const int* __restrict__ off, int* __restrict__ pos,
            uint2* __restrict__ rec, float* __restrict__ asum_mid)
{
  __shared__ __align__(16) float ea[64*EA_LD];
  __shared__ __align__(16) float Wt[32*128];
  const int tid = threadIdx.x;
  const int e0 = blockIdx.x * 64;   // E divisible by 64
  const int c4 = tid & 31, kb = tid >> 5;
  {
    const int q = tid & 63, eb = tid >> 6;
#pragma unroll
    for (int i = 0; i < 16; ++i){
      int e = eb + 4*i;
      *(float2*)&ea[e*EA_LD + q*2] = *(const float2*)&edge_attr[(e0+e)*DD + q*2];
    }
    float4 w0[4];
#pragma unroll
    for (int i = 0; i < 4; ++i)
      w0[i] = *(const float4*)&W_edge[(kb + 8*i)*DD + c4*4];
#pragma unroll
    for (int i = 0; i < 4; ++i)
      *(float4*)&Wt[(kb + 8*i)*128 + c4*4] = w0[i];
  }
  __syncthreads();

  const int eg = tid >> 4;
  const int cg = tid & 15;
  float acc[4][8];
#pragma unroll
  for (int j = 0; j < 4; ++j)
#pragma unroll
    for (int u = 0; u < 8; ++u) acc[j][u] = 0.f;

  for (int kq = 0; kq < 4; ++kq){
    float4 wreg[4];
    if (kq < 3){
#pragma unroll
      for (int i = 0; i < 4; ++i)
        wreg[i] = *(const float4*)&W_edge[((kq+1)*32 + kb + 8*i)*DD + c4*4];
    }
    const int kb2 = kq*32;
#pragma unroll 2
    for (int kp = 0; kp < 16; ++kp){
      float2 aa[4];
#pragma unroll
      for (int j = 0; j < 4; ++j)
        aa[j] = *(const float2*)&ea[(eg*4+j)*EA_LD + kb2 + kp*2];
      float bb[16];
      *(float4*)&bb[0]  = *(const float4*)&Wt[(kp*2)*128 + cg*4];
      *(float4*)&bb[4]  = *(const float4*)&Wt[(kp*2)*128 + 64 + cg*4];
      *(float4*)&bb[8]  = *(const float4*)&Wt[(kp*2+1)*128 + cg*4];
      *(float4*)&bb[12] = *(const float4*)&Wt[(kp*2+1)*128 + 64 + cg*4];
#pragma unroll
      for (int j = 0; j < 4; ++j){
#pragma unroll
        for (int u = 0; u < 8; ++u) acc[j][u] = fmaf(aa[j].x, bb[u],   acc[j][u]);
#pragma unroll
        for (int u = 0; u < 8; ++u) acc[j][u] = fmaf(aa[j].y, bb[8+u], acc[j][u]);
      }
    }
    if (kq < 3){
      __syncthreads();
#pragma unroll
      for (int i = 0; i < 4; ++i)
        *(float4*)&Wt[(kb + 8*i)*128 + c4*4] = wreg[i];
      __syncthreads();
    }
  }
  // epilogue: add xl[src] + xr[dst], leaky-relu, dot with att, reduce over cg
  float attv[8];
  *(float4*)&attv[0] = *(const float4*)&att[cg*4];
  *(float4*)&attv[4] = *(const float4*)&att[64 + cg*4];
  float sp[4];
  int dsts[4], srcs[4];
#pragma unroll
  for (int j = 0; j < 4; ++j){
    int e = e0 + eg*4 + j;
    int s = ei[e];
    int d = ei[E_EDGES + e];
    srcs[j] = s; dsts[j] = d;
    float xlv[8], xrv[8];
    *(float4*)&xlv[0] = *(const float4*)&xl[s*DD + cg*4];
    *(float4*)&xlv[4] = *(const float4*)&xl[s*DD + 64 + cg*4];
    *(float4*)&xrv[0] = *(const float4*)&xr[d*DD + cg*4];
    *(float4*)&xrv[4] = *(const float4*)&xr[d*DD + 64 + cg*4];
    float p = 0.f;
#pragma unroll
    for (int u = 0; u < 8; ++u){
      float vv = acc[j][u] + xlv[u] + xrv[u];
      p += lrelu(vv) * attv[u];
    }
    sp[j] = p;
  }
#pragma unroll
  for (int m = 1; m < 16; m <<= 1){
#pragma unroll
    for (int j = 0; j < 4; ++j) sp[j] += __shfl_xor(sp[j], m);
  }
  if (cg == 0){
#pragma unroll
    for (int j = 0; j < 4; ++j){
      int d = dsts[j];
      int p = atomicAdd(&pos[d], 1);
      uint2 r;
      r.x = (unsigned)srcs[j];
      r.y = __float_as_uint(sp[j]);
      rec[off[d] + p] = r;
    }
  }
  // fused edge_attr column-sum partials (for mean_attr)
  if (tid < 128){
    float s = 0.f;
    for (int e = 0; e < 64; ++e) s += ea[e*EA_LD + tid];
    atomicAdd(&asum_mid[(blockIdx.x & 63)*DD + tid], s);
  }
}

// ---------------- me = (col_sum/E) @ W_edge ----------------
__global__ __launch_bounds__(128)
void k_me(const float* __restrict__ asum_mid, const float* __restrict__ W_edge,
          float* __restrict__ me)
{
  __shared__ float mean[128];
  const int d = threadIdx.x;
  float s = 0.f;
  for (int r = 0; r < 64; ++r) s += asum_mid[r*DD + d];
  mean[d] = s / (float)E_EDGES;
  __syncthreads();
  float acc = 0.f;
  for (int k = 0; k < 128; ++k) acc += mean[k] * W_edge[k*DD + d];
  me[d] = acc;
}

// ---------------- in-degree histogram ----------------
__global__ __launch_bounds__(256)
void k_hist(const int* __restrict__ ei, int* __restrict__ indeg)
{
  int e = blockIdx.x*256 + threadIdx.x;
  if (e < E_EDGES) atomicAdd(&indeg[ei[E_EDGES + e]], 1);
}

// ---------------- parallel scan: 98 blocks x 512 ----------------
#define SC_NB ((N_NODES + 511) / 512)
__global__ __launch_bounds__(512)
void k_scan1(const int* __restrict__ indeg, int* __restrict__ off, int* __restrict__ bsum)
{
  __shared__ int s[512];
  const int tid = threadIdx.x;
  const int gid = blockIdx.x*512 + tid;
  int v = (gid < N_NODES) ? indeg[gid] : 0;
  s[tid] = v;
  __syncthreads();
  for (int d = 1; d < 512; d <<= 1){
    int t = (tid >= d) ? s[tid-d] : 0;
    __syncthreads();
    s[tid] += t;
    __syncthreads();
  }
  if (gid < N_NODES) off[gid] = s[tid] - v;   // block-local exclusive
  if (tid == 511) bsum[blockIdx.x] = s[511];
}

__global__ __launch_bounds__(128)
void k_scan2(const int* __restrict__ bsum, int* __restrict__ boff)
{
  __shared__ int s[128];
  const int tid = threadIdx.x;
  int v = (tid < SC_NB) ? bsum[tid] : 0;
  s[tid] = v;
  __syncthreads();
  for (int d = 1; d < 128; d <<= 1){
    int t = (tid >= d) ? s[tid-d] : 0;
    __syncthreads();
    s[tid] += t;
    __syncthreads();
  }
  if (tid < SC_NB) boff[tid] = s[tid] - v;    // exclusive
}

__global__ __launch_bounds__(512)
void k_scan3(int* __restrict__ off, const int* __restrict__ boff)
{
  const int gid = blockIdx.x*512 + threadIdx.x;
  if (gid < N_NODES) off[gid] += boff[blockIdx.x];
  if (gid == 0) off[N_NODES] = E_EDGES;
}

// ------- per-node softmax-aggregate (one wave/node) + pooled block-reduced atomic add -------
__global__ __launch_bounds__(256)
void k_aggregate(const int* __restrict__ off, const uint2* __restrict__ rec,
                 const float* __restrict__ xl, const float* __restrict__ xr,
                 const float* __restrict__ me, const float* __restrict__ att,
                 const float* __restrict__ conv_bias, const int* __restrict__ batch_vec,
                 float* __restrict__ gsum, float* __restrict__ gcnt)
{
  __shared__ float hshare[4][128];
  __shared__ int bsh[4];
  const int tid = threadIdx.x, lane = tid & 63, wid = tid >> 6;
  const int i = blockIdx.x*4 + wid;   // 12500*4 == N exactly
  float2 xli = *(const float2*)&xl[i*DD + lane*2];
  float2 xri = *(const float2*)&xr[i*DD + lane*2];
  float2 mev = *(const float2*)&me[lane*2];
  float2 attv = *(const float2*)&att[lane*2];
  float v0 = xli.x + xri.x + mev.x;
  float v1 = xli.y + xri.y + mev.y;
  float s_self = wsum(lrelu(v0)*attv.x + lrelu(v1)*attv.y);
  const int o0 = off[i], o1 = off[i+1];
  const int deg = o1 - o0;
  // pass 1: max (keep first chunk's records in registers)
  uint2 myrec = make_uint2(0u, __float_as_uint(-INFINITY));
  float m = s_self;
  if (lane < deg) myrec = rec[o0 + lane];
  m = fmaxf(m, __uint_as_float(myrec.y));
  for (int b = 64; b < deg; b += 64){
    int j = b + lane;
    if (j < deg) m = fmaxf(m, __uint_as_float(rec[o0 + j].y));
  }
  m = wmax(m);
  // pass 2
  float wse = __expf(s_self - m);
  float den = wse;
  float a0 = wse * xli.x, a1 = wse * xli.y;
  if (deg <= 64){
    float msc = __uint_as_float(myrec.y);
    int msrc = (int)myrec.x;
#pragma unroll 4
    for (int j = 0; j < deg; ++j){
      float sc = __shfl(msc, j);
      int s = __shfl(msrc, j);
      float w = __expf(sc - m);
      den += w;
      float2 xs = *(const float2*)&xl[s*DD + lane*2];
      a0 = fmaf(w, xs.x, a0);
      a1 = fmaf(w, xs.y, a1);
    }
  } else {
#pragma unroll 4
    for (int j = 0; j < deg; ++j){
      uint2 r = rec[o0 + j];
      float w = __expf(__uint_as_float(r.y) - m);
      den += w;
      float2 xs = *(const float2*)&xl[(int)r.x*DD + lane*2];
      a0 = fmaf(w, xs.x, a0);
      a1 = fmaf(w, xs.y, a1);
    }
  }
  float inv = 1.0f / (den + 1e-16f);
  float2 cb2 = *(const float2*)&conv_bias[lane*2];
  float h0 = a0*inv + cb2.x;
  float h1 = a1*inv + cb2.y;
  int b = batch_vec[i];
  hshare[wid][lane*2]     = h0;
  hshare[wid][lane*2 + 1] = h1;
  if (lane == 0) bsh[wid] = b;
  __syncthreads();
  bool uni = (bsh[0]==bsh[1]) && (bsh[1]==bsh[2]) && (bsh[2]==bsh[3]);
  if (uni){
    if (wid == 0){
      float s0 = hshare[0][lane*2] + hshare[1][lane*2] + hshare[2][lane*2] + hshare[3][lane*2];
      float s1 = hshare[0][lane*2+1] + hshare[1][lane*2+1] + hshare[2][lane*2+1] + hshare[3][lane*2+1];
      atomicAdd(&gsum[b*DD + lane*2],     s0);
      atomicAdd(&gsum[b*DD + lane*2 + 1], s1);
      if (lane == 0) atomicAdd(&gcnt[b], 4.0f);
    }
  } else {
    atomicAdd(&gsum[b*DD + lane*2],     h0);
    atomicAdd(&gsum[b*DD + lane*2 + 1], h1);
    if (lane == 0) atomicAdd(&gcnt[b], 1.0f);
  }
}

// ---------------- pool-divide + adapter + layernorm ----------------
__global__ __launch_bounds__(128)
void k_pool(const float* __restrict__ gsum, const float* __restrict__ gcnt,
            const float* __restrict__ aW, const float* __restrict__ ab,
            const float* __restrict__ ng, const float* __restrict__ nb,
            float* __restrict__ g_ln)
{
  __shared__ float row[128];
  __shared__ float red[128];
  const int g = blockIdx.x, d = threadIdx.x;
  float denom = fmaxf(gcnt[g], 1.0f);
  row[d] = gsum[g*DD + d] / denom;
  __syncthreads();
  double accd = (double)ab[d];
  for (int k = 0; k < 128; ++k) accd += (double)row[k] * (double)aW[k*DD + d];
  float a = (float)accd;
  red[d] = a; __syncthreads();
  for (int s = 64; s > 0; s >>= 1){ if (d < s) red[d] += red[d+s]; __syncthreads(); }
  float mean = red[0] / 128.f; __syncthreads();
  float c = a - mean;
  red[d] = c*c; __syncthreads();
  for (int s = 64; s > 0; s >>= 1){ if (d < s) red[d] += red[d+s]; __syncthreads(); }
  float var = red[0] / 128.f; __syncthreads();
  float inv = (float)(1.0 / sqrt((double)var + (double)LN_EPS));
  g_ln[g*DD + d] = c * inv * ng[d] + nb[d];
}

// ---------------- residual VQ (Q=3, K=512) ----------------
__global__ __launch_bounds__(256)
void k_rvq(const float* __restrict__ g_ln, const float* __restrict__ codebooks,
           float* __restrict__ ind_out, int* __restrict__ idx_i,
           float* __restrict__ accs)
{
  __shared__ __align__(16) float r_lds[128];
  __shared__ float red[128];
  __shared__ double bd[64];
  __shared__ int bi[64];
  __shared__ int chosen;
  const int g = blockIdx.x, tid = threadIdx.x;
  if (tid < 128) r_lds[tid] = g_ln[g*DD + tid];
  __syncthreads();
  const int cl = tid >> 2, dq = tid & 3;
  for (int q = 0; q < Q_QUANT; ++q){
    const float* cb = codebooks + (size_t)q * K_CODES * DD;
    double bestd = 1e300; int besti = 1 << 30;
    for (int r = 0; r < 8; ++r){
      int c = r*64 + cl;
      double rc = 0.0, cc = 0.0;
      const float4* cp = (const float4*)&cb[c*DD + dq*32];
      const float4* rp = (const float4*)&r_lds[dq*32];
#pragma unroll
      for (int i = 0; i < 8; ++i){
        float4 cv = cp[i]; float4 rv = rp[i];
        rc += (double)cv.x*rv.x + (double)cv.y*rv.y + (double)cv.z*rv.z + (double)cv.w*rv.w;
        cc += (double)cv.x*cv.x + (double)cv.y*cv.y + (double)cv.z*cv.z + (double)cv.w*cv.w;
      }
      rc += __shfl_xor(rc, 1); rc += __shfl_xor(rc, 2);
      cc += __shfl_xor(cc, 1); cc += __shfl_xor(cc, 2);
      if (dq == 0){
        double d2 = cc - 2.0*rc;
        if (d2 < bestd || (d2 == bestd && c < besti)){ bestd = d2; besti = c; }
      }
    }
    if (dq == 0){ bd[cl] = bestd; bi[cl] = besti; }
    __syncthreads();
    if (tid < 64){
      double d2 = bd[tid]; int ii = bi[tid];
#pragma unroll
      for (int m = 1; m < 64; m <<= 1){
        double od = __shfl_xor(d2, m); int oi = __shfl_xor(ii, m);
        if (od < d2 || (od == d2 && oi < ii)){ d2 = od; ii = oi; }
      }
      if (tid == 0) chosen = ii;
    }
    __syncthreads();
    const int idx = chosen;
    if (tid == 0){
      ind_out[g*Q_QUANT + q] = (float)idx;
      idx_i[g*Q_QUANT + q] = idx;
    }
    if (tid < 128){
      float cd = cb[idx*DD + tid];
      float diff = cd - r_lds[tid];
      red[tid] = diff * diff;
      r_lds[tid] -= cd;
    }
    __syncthreads();
    for (int s = 64; s > 0; s >>= 1){ if (tid < s) red[tid] += red[tid+s]; __syncthreads(); }
    if (tid == 0) atomicAdd(&accs[q], red[0]);
    __syncthreads();
  }
  if (tid < 128) red[tid] = r_lds[tid]*r_lds[tid];
  __syncthreads();
  for (int s = 64; s > 0; s >>= 1){ if (tid < s) red[tid] += red[tid+s]; __syncthreads(); }
  if (tid == 0) atomicAdd(&accs[3], red[0]);
}

// ---------------- tokens: LN(code @ out_W + out_b) ----------------
__global__ __launch_bounds__(256)
void k_tokens(const float* __restrict__ codebooks, const int* __restrict__ idx_i,
              const float* __restrict__ out_W, const float* __restrict__ out_b,
              const float* __restrict__ og, const float* __restrict__ ob,
              float* __restrict__ tokens)
{
  __shared__ __align__(16) float c_lds[128];
  __shared__ float red[256];
  const int blk = blockIdx.x;
  const int g = blk / 3, q = blk % 3;
  const int tid = threadIdx.x;
  const int idx = idx_i[g*Q_QUANT + q];
  if (tid < 128) c_lds[tid] = codebooks[((size_t)q*K_CODES + idx)*DD + tid];
  __syncthreads();
  double v0 = (double)out_b[tid];
  double v1 = (double)out_b[tid + 256];
  for (int k = 0; k < 128; ++k){
    double ck = (double)c_lds[k];
    v0 += ck * (double)out_W[k*FD_OUT + tid];
    v1 += ck * (double)out_W[k*FD_OUT + tid + 256];
  }
  float f0 = (float)v0, f1 = (float)v1;
  red[tid] = f0 + f1; __syncthreads();
  for (int s = 128; s > 0; s >>= 1){ if (tid < s) red[tid] += red[tid+s]; __syncthreads(); }
  float mean = red[0] / 512.f; __syncthreads();
  float d0 = f0 - mean, d1 = f1 - mean;
  red[tid] = d0*d0 + d1*d1; __syncthreads();
  for (int s = 128; s > 0; s >>= 1){ if (tid < s) red[tid] += red[tid+s]; __syncthreads(); }
  float var = red[0] / 512.f; __syncthreads();
  float inv = (float)(1.0 / sqrt((double)var + (double)LN_EPS));
  tokens[(size_t)blk*FD_OUT + tid]       = d0*inv*og[tid] + ob[tid];
  tokens[(size_t)blk*FD_OUT + tid + 256] = d1*inv*og[tid+256] + ob[tid+256];
}

// ---------------- loss ----------------
__global__ void k_loss(const float* __restrict__ accs, float* __restrict__ out)
{
  float commit = (accs[0] + accs[1] + accs[2]) / (3.0f * G_GRAPHS * DD);
  float resid  = accs[3] / ((float)G_GRAPHS * DD);
  out[0] = commit + resid;
}

extern "C" void kernel_launch(void* const* d_in, const int* in_sizes, int n_in,
                              void* d_out, int out_size, void* d_ws, size_t ws_size,
                              hipStream_t stream)
{
  (void)in_sizes; (void)n_in; (void)out_size; (void)ws_size;
  const float* x         = (const float*)d_in[0];
  const int*   ei        = (const int*)d_in[1];
  const float* edge_attr = (const float*)d_in[2];
  const int*   batch_vec = (const int*)d_in[3];
  const float* W_l       = (const float*)d_in[4];
  const float* b_l       = (const float*)d_in[5];
  const float* W_r       = (const float*)d_in[6];
  const float* b_r       = (const float*)d_in[7];
  const float* W_edge    = (const float*)d_in[8];
  const float* att       = (const float*)d_in[9];
  const float* conv_bias = (const float*)d_in[10];
  const float* aW        = (const float*)d_in[11];
  const float* ab        = (const float*)d_in[12];
  const float* ng        = (const float*)d_in[13];
  const float* nb        = (const float*)d_in[14];
  const float* codebooks = (const float*)d_in[15];
  const float* out_W     = (const float*)d_in[16];
  const float* out_b     = (const float*)d_in[17];
  const float* og        = (const float*)d_in[18];
  const float* ob        = (const float*)d_in[19];
  float* outf = (float*)d_out;

  char* w = (char*)d_ws;
  size_t o = 0;
  auto nxt = [&](size_t bytes)->void*{
    void* p = w + o;
    o += (bytes + 511) & ~(size_t)511;
    return p;
  };
  // --- zeroed buffers first (single memset over the span) ---
  int*   indeg    = (int*)  nxt((size_t)N_NODES*4);
  int*   pos      = (int*)  nxt((size_t)N_NODES*4);
  float* asum_mid = (float*)nxt((size_t)64*DD*4);
  float* gsum     = (float*)nxt((size_t)G_GRAPHS*DD*4);
  float* gcnt     = (float*)nxt((size_t)G_GRAPHS*4);
  float* accs     = (float*)nxt(16);
  const size_t zero_span = o;
  // --- non-zeroed ---
  int*   off      = (int*)  nxt((size_t)(N_NODES+1)*4);
  float* xl       = (float*)nxt((size_t)N_NODES*DD*4);
  float* xr       = (float*)nxt((size_t)N_NODES*DD*4);
  uint2* rec      = (uint2*)nxt((size_t)E_EDGES*8);
  float* me       = (float*)nxt((size_t)DD*4);
  float* g_ln     = (float*)nxt((size_t)G_GRAPHS*DD*4);
  int*   idx_i    = (int*)  nxt((size_t)G_GRAPHS*Q_QUANT*4);
  int*   bsum     = (int*)  nxt((size_t)SC_NB*4);
  int*   boff     = (int*)  nxt((size_t)SC_NB*4);

  hipMemsetAsync(w, 0, zero_span, stream);

  k_hist<<<dim3((E_EDGES+255)/256), dim3(256), 0, stream>>>(ei, indeg);
  k_scan1<<<dim3(SC_NB), dim3(512), 0, stream>>>(indeg, off, bsum);
  k_scan2<<<dim3(1), dim3(128), 0, stream>>>(bsum, boff);
  k_scan3<<<dim3(SC_NB), dim3(512), 0, stream>>>(off, boff);
  k_xform2<<<dim3((N_NODES+63)/64), dim3(256), 0, stream>>>(x, W_l, b_l, W_r, b_r,
                                                            xl, xr, N_NODES);
  k_edge<<<dim3(E_EDGES/64), dim3(256), 0, stream>>>(edge_attr, W_edge, ei, xl, xr, att,
                                                     off, pos, rec, asum_mid);
  k_me<<<dim3(1), dim3(128), 0, stream>>>(asum_mid, W_edge, me);
  k_aggregate<<<dim3(N_NODES/4), dim3(256), 0, stream>>>(off, rec, xl, xr, me, att,
                                                         conv_bias, batch_vec, gsum, gcnt);
  k_pool<<<dim3(G_GRAPHS), dim3(128), 0, stream>>>(gsum, gcnt, aW, ab, ng, nb, g_ln);
  k_rvq<<<dim3(G_GRAPHS), dim3(256), 0, stream>>>(g_ln, codebooks,
                                                  outf + (size_t)G_GRAPHS*Q_QUANT*FD_OUT,
                                                  idx_i, accs);
  k_tokens<<<dim3(G_GRAPHS*Q_QUANT), dim3(256), 0, stream>>>(codebooks, idx_i, out_W, out_b,
                                                             og, ob, outf);
  k_loss<<<dim3(1), dim3(1), 0, stream>>>(accs,
                                          outf + (size_t)G_GRAPHS*Q_QUANT*FD_OUT
                                               + (size_t)G_GRAPHS*Q_QUANT);
}

// Round 5
// 580.513 us; speedup vs baseline: 1.4701x; 1.1461x over previous
//
#include <hip/hip_runtime.h>
#include <math.h>

#define N_NODES 50000
#define E_EDGES 600000
#define DD 128
#define G_GRAPHS 512
#define K_CODES 512
#define Q_QUANT 3
#define FD_OUT 512
#define NEG_SLOPE 0.2f
#define LN_EPS 1e-5f

static __device__ __forceinline__ float lrelu(float v){ return v > 0.f ? v : NEG_SLOPE*v; }
static __device__ __forceinline__ float wsum(float v){
#pragma unroll
  for (int m = 1; m < 64; m <<= 1) v += __shfl_xor(v, m);
  return v;
}
static __device__ __forceinline__ float wmax(float v){
#pragma unroll
  for (int m = 1; m < 64; m <<= 1) v = fmaxf(v, __shfl_xor(v, m));
  return v;
}

#define EA_LD 130   // row pitch: 520B -> A-broadcast addrs land on distinct banks

// ---------------- fused transform: xl = x@W_l + b_l ; xr = x@W_r + b_r ----------------
// shared x tile + shared A-reads feed both accumulators; per-kq barrier W staging
// (round-3-proven staging pattern; no register prefetch -> no spill risk)
__global__ __launch_bounds__(256)
void k_xform2(const float* __restrict__ x,
              const float* __restrict__ W_l, const float* __restrict__ b_l,
              const float* __restrict__ W_r, const float* __restrict__ b_r,
              float* __restrict__ xl, float* __restrict__ xr, int n)
{
  __shared__ __align__(16) float xt[64*EA_LD];
  __shared__ __align__(16) float WtL[32*128];
  __shared__ __align__(16) float WtR[32*128];
  const int tid = threadIdx.x;
  const int r0 = blockIdx.x * 64;
  {
    const int q = tid & 63, eb = tid >> 6;
#pragma unroll
    for (int i = 0; i < 16; ++i){
      int e = eb + 4*i;
      int row = r0 + e;
      float2 v = make_float2(0.f, 0.f);
      if (row < n) v = *(const float2*)&x[row*DD + q*2];
      *(float2*)&xt[e*EA_LD + q*2] = v;
    }
  }
  const int eg = tid >> 4;
  const int cg = tid & 15;
  float accL[4][8], accR[4][8];
#pragma unroll
  for (int j = 0; j < 4; ++j)
#pragma unroll
    for (int u = 0; u < 8; ++u){ accL[j][u] = 0.f; accR[j][u] = 0.f; }

  for (int kq = 0; kq < 4; ++kq){
    __syncthreads();
    {
      const int c4 = tid & 31, kb = tid >> 5;
#pragma unroll
      for (int i = 0; i < 4; ++i){
        int kk = kb + 8*i;
        *(float4*)&WtL[kk*128 + c4*4] = *(const float4*)&W_l[(kq*32+kk)*DD + c4*4];
        *(float4*)&WtR[kk*128 + c4*4] = *(const float4*)&W_r[(kq*32+kk)*DD + c4*4];
      }
    }
    __syncthreads();
    const int kb2 = kq*32;
#pragma unroll 4
    for (int k = 0; k < 32; ++k){
      float aa[4];
#pragma unroll
      for (int j = 0; j < 4; ++j) aa[j] = xt[(eg*4+j)*EA_LD + kb2 + k];
      float bL[8], bR[8];
      *(float4*)&bL[0] = *(const float4*)&WtL[k*128 + cg*4];
      *(float4*)&bL[4] = *(const float4*)&WtL[k*128 + 64 + cg*4];
      *(float4*)&bR[0] = *(const float4*)&WtR[k*128 + cg*4];
      *(float4*)&bR[4] = *(const float4*)&WtR[k*128 + 64 + cg*4];
#pragma unroll
      for (int j = 0; j < 4; ++j){
#pragma unroll
        for (int u = 0; u < 8; ++u) accL[j][u] = fmaf(aa[j], bL[u], accL[j][u]);
#pragma unroll
        for (int u = 0; u < 8; ++u) accR[j][u] = fmaf(aa[j], bR[u], accR[j][u]);
      }
    }
  }
  float bvL[8], bvR[8];
  *(float4*)&bvL[0] = *(const float4*)&b_l[cg*4];
  *(float4*)&bvL[4] = *(const float4*)&b_l[64 + cg*4];
  *(float4*)&bvR[0] = *(const float4*)&b_r[cg*4];
  *(float4*)&bvR[4] = *(const float4*)&b_r[64 + cg*4];
#pragma unroll
  for (int j = 0; j < 4; ++j){
    int row = r0 + eg*4 + j;
    if (row < n){
      float oL[8], oR[8];
#pragma unroll
      for (int u = 0; u < 8; ++u){ oL[u] = accL[j][u] + bvL[u]; oR[u] = accR[j][u] + bvR[u]; }
      *(float4*)&xl[row*DD + cg*4]      = *(const float4*)&oL[0];
      *(float4*)&xl[row*DD + 64 + cg*4] = *(const float4*)&oL[4];
      *(float4*)&xr[row*DD + cg*4]      = *(const float4*)&oR[0];
      *(float4*)&xr[row*DD + 64 + cg*4] = *(const float4*)&oR[4];
    }
  }
}

// --------- per-edge score: e_emb = ea@W_edge (fused), score = lrelu(e).att ---------
// fused: edge_attr column-sums (for mean_attr) and direct CSR scatter of (src,score)
// EXACT round-3 body (proven 303us, 0 conflicts, no spills)
__global__ __launch_bounds__(256)
void k_edge(const float* __restrict__ edge_attr, const float* __restrict__ W_edge,
            const int* __restrict__ ei, const float* __restrict__ xl,
            const float* __restrict__ xr, const float* __restrict__ att,
            const int* __restrict__ off, int* __restrict__ pos,
            uint2* __restrict__ rec, float* __restrict__ asum_mid)
{
  __shared__ __align__(16) float ea[64*EA_LD];
  __shared__ __align__(16) float Wt[32*128];
  const int tid = threadIdx.x;
  const int e0 = blockIdx.x * 64;   // E divisible by 64
  {
    const int q = tid & 63, eb = tid >> 6;
#pragma unroll
    for (int i = 0; i < 16; ++i){
      int e = eb + 4*i;
      *(float2*)&ea[e*EA_LD + q*2] = *(const float2*)&edge_attr[(e0+e)*DD + q*2];
    }
  }
  const int eg = tid >> 4;
  const int cg = tid & 15;
  float acc[4][8];
#pragma unroll
  for (int j = 0; j < 4; ++j)
#pragma unroll
    for (int u = 0; u < 8; ++u) acc[j][u] = 0.f;

  for (int kq = 0; kq < 4; ++kq){
    __syncthreads();
    {
      const int c4 = tid & 31, kb = tid >> 5;
#pragma unroll
      for (int i = 0; i < 4; ++i){
        int kk = kb + 8*i;
        *(float4*)&Wt[kk*128 + c4*4] = *(const float4*)&W_edge[(kq*32+kk)*DD + c4*4];
      }
    }
    __syncthreads();
    const int kb2 = kq*32;
#pragma unroll 4
    for (int k = 0; k < 32; ++k){
      float aa[4];
#pragma unroll
      for (int j = 0; j < 4; ++j) aa[j] = ea[(eg*4+j)*EA_LD + kb2 + k];
      float bb[8];
      *(float4*)&bb[0] = *(const float4*)&Wt[k*128 + cg*4];
      *(float4*)&bb[4] = *(const float4*)&Wt[k*128 + 64 + cg*4];
#pragma unroll
      for (int j = 0; j < 4; ++j)
#pragma unroll
        for (int u = 0; u < 8; ++u) acc[j][u] = fmaf(aa[j], bb[u], acc[j][u]);
    }
  }
  // epilogue: add xl[src] + xr[dst], leaky-relu, dot with att, reduce over cg
  float attv[8];
  *(float4*)&attv[0] = *(const float4*)&att[cg*4];
  *(float4*)&attv[4] = *(const float4*)&att[64 + cg*4];
  float sp[4];
  int dsts[4], srcs[4];
#pragma unroll
  for (int j = 0; j < 4; ++j){
    int e = e0 + eg*4 + j;
    int s = ei[e];
    int d = ei[E_EDGES + e];
    srcs[j] = s; dsts[j] = d;
    float xlv[8], xrv[8];
    *(float4*)&xlv[0] = *(const float4*)&xl[s*DD + cg*4];
    *(float4*)&xlv[4] = *(const float4*)&xl[s*DD + 64 + cg*4];
    *(float4*)&xrv[0] = *(const float4*)&xr[d*DD + cg*4];
    *(float4*)&xrv[4] = *(const float4*)&xr[d*DD + 64 + cg*4];
    float p = 0.f;
#pragma unroll
    for (int u = 0; u < 8; ++u){
      float vv = acc[j][u] + xlv[u] + xrv[u];
      p += lrelu(vv) * attv[u];
    }
    sp[j] = p;
  }
#pragma unroll
  for (int m = 1; m < 16; m <<= 1){
#pragma unroll
    for (int j = 0; j < 4; ++j) sp[j] += __shfl_xor(sp[j], m);
  }
  if (cg == 0){
#pragma unroll
    for (int j = 0; j < 4; ++j){
      int d = dsts[j];
      int p = atomicAdd(&pos[d], 1);
      uint2 r;
      r.x = (unsigned)srcs[j];
      r.y = __float_as_uint(sp[j]);
      rec[off[d] + p] = r;
    }
  }
  // fused edge_attr column-sum partials (for mean_attr)
  if (tid < 128){
    float s = 0.f;
    for (int e = 0; e < 64; ++e) s += ea[e*EA_LD + tid];
    atomicAdd(&asum_mid[(blockIdx.x & 63)*DD + tid], s);
  }
}

// ---------------- me = (col_sum/E) @ W_edge ----------------
__global__ __launch_bounds__(128)
void k_me(const float* __restrict__ asum_mid, const float* __restrict__ W_edge,
          float* __restrict__ me)
{
  __shared__ float mean[128];
  const int d = threadIdx.x;
  float s = 0.f;
  for (int r = 0; r < 64; ++r) s += asum_mid[r*DD + d];
  mean[d] = s / (float)E_EDGES;
  __syncthreads();
  float acc = 0.f;
  for (int k = 0; k < 128; ++k) acc += mean[k] * W_edge[k*DD + d];
  me[d] = acc;
}

// ---------------- in-degree histogram ----------------
__global__ __launch_bounds__(256)
void k_hist(const int* __restrict__ ei, int* __restrict__ indeg)
{
  int e = blockIdx.x*256 + threadIdx.x;
  if (e < E_EDGES) atomicAdd(&indeg[ei[E_EDGES + e]], 1);
}

// ---------------- parallel scan: 98 blocks x 512 ----------------
#define SC_NB ((N_NODES + 511) / 512)
__global__ __launch_bounds__(512)
void k_scan1(const int* __restrict__ indeg, int* __restrict__ off, int* __restrict__ bsum)
{
  __shared__ int s[512];
  const int tid = threadIdx.x;
  const int gid = blockIdx.x*512 + tid;
  int v = (gid < N_NODES) ? indeg[gid] : 0;
  s[tid] = v;
  __syncthreads();
  for (int d = 1; d < 512; d <<= 1){
    int t = (tid >= d) ? s[tid-d] : 0;
    __syncthreads();
    s[tid] += t;
    __syncthreads();
  }
  if (gid < N_NODES) off[gid] = s[tid] - v;   // block-local exclusive
  if (tid == 511) bsum[blockIdx.x] = s[511];
}

__global__ __launch_bounds__(128)
void k_scan2(const int* __restrict__ bsum, int* __restrict__ boff)
{
  __shared__ int s[128];
  const int tid = threadIdx.x;
  int v = (tid < SC_NB) ? bsum[tid] : 0;
  s[tid] = v;
  __syncthreads();
  for (int d = 1; d < 128; d <<= 1){
    int t = (tid >= d) ? s[tid-d] : 0;
    __syncthreads();
    s[tid] += t;
    __syncthreads();
  }
  if (tid < SC_NB) boff[tid] = s[tid] - v;    // exclusive
}

__global__ __launch_bounds__(512)
void k_scan3(int* __restrict__ off, const int* __restrict__ boff)
{
  const int gid = blockIdx.x*512 + threadIdx.x;
  if (gid < N_NODES) off[gid] += boff[blockIdx.x];
  if (gid == 0) off[N_NODES] = E_EDGES;
}

// ------- per-node softmax-aggregate (one wave/node) + pooled block-reduced atomic add -------
__global__ __launch_bounds__(256)
void k_aggregate(const int* __restrict__ off, const uint2* __restrict__ rec,
                 const float* __restrict__ xl, const float* __restrict__ xr,
                 const float* __restrict__ me, const float* __restrict__ att,
                 const float* __restrict__ conv_bias, const int* __restrict__ batch_vec,
                 float* __restrict__ gsum, float* __restrict__ gcnt)
{
  __shared__ float hshare[4][128];
  __shared__ int bsh[4];
  const int tid = threadIdx.x, lane = tid & 63, wid = tid >> 6;
  const int i = blockIdx.x*4 + wid;   // 12500*4 == N exactly
  float2 xli = *(const float2*)&xl[i*DD + lane*2];
  float2 xri = *(const float2*)&xr[i*DD + lane*2];
  float2 mev = *(const float2*)&me[lane*2];
  float2 attv = *(const float2*)&att[lane*2];
  float v0 = xli.x + xri.x + mev.x;
  float v1 = xli.y + xri.y + mev.y;
  float s_self = wsum(lrelu(v0)*attv.x + lrelu(v1)*attv.y);
  const int o0 = off[i], o1 = off[i+1];
  const int deg = o1 - o0;
  // pass 1: max (keep first chunk's records in registers)
  uint2 myrec = make_uint2(0u, __float_as_uint(-INFINITY));
  float m = s_self;
  if (lane < deg) myrec = rec[o0 + lane];
  m = fmaxf(m, __uint_as_float(myrec.y));
  for (int b = 64; b < deg; b += 64){
    int j = b + lane;
    if (j < deg) m = fmaxf(m, __uint_as_float(rec[o0 + j].y));
  }
  m = wmax(m);
  // pass 2
  float wse = __expf(s_self - m);
  float den = wse;
  float a0 = wse * xli.x, a1 = wse * xli.y;
  if (deg <= 64){
    float msc = __uint_as_float(myrec.y);
    int msrc = (int)myrec.x;
#pragma unroll 4
    for (int j = 0; j < deg; ++j){
      float sc = __shfl(msc, j);
      int s = __shfl(msrc, j);
      float w = __expf(sc - m);
      den += w;
      float2 xs = *(const float2*)&xl[s*DD + lane*2];
      a0 = fmaf(w, xs.x, a0);
      a1 = fmaf(w, xs.y, a1);
    }
  } else {
#pragma unroll 4
    for (int j = 0; j < deg; ++j){
      uint2 r = rec[o0 + j];
      float w = __expf(__uint_as_float(r.y) - m);
      den += w;
      float2 xs = *(const float2*)&xl[(int)r.x*DD + lane*2];
      a0 = fmaf(w, xs.x, a0);
      a1 = fmaf(w, xs.y, a1);
    }
  }
  float inv = 1.0f / (den + 1e-16f);
  float2 cb2 = *(const float2*)&conv_bias[lane*2];
  float h0 = a0*inv + cb2.x;
  float h1 = a1*inv + cb2.y;
  int b = batch_vec[i];
  hshare[wid][lane*2]     = h0;
  hshare[wid][lane*2 + 1] = h1;
  if (lane == 0) bsh[wid] = b;
  __syncthreads();
  bool uni = (bsh[0]==bsh[1]) && (bsh[1]==bsh[2]) && (bsh[2]==bsh[3]);
  if (uni){
    if (wid == 0){
      float s0 = hshare[0][lane*2] + hshare[1][lane*2] + hshare[2][lane*2] + hshare[3][lane*2];
      float s1 = hshare[0][lane*2+1] + hshare[1][lane*2+1] + hshare[2][lane*2+1] + hshare[3][lane*2+1];
      atomicAdd(&gsum[b*DD + lane*2],     s0);
      atomicAdd(&gsum[b*DD + lane*2 + 1], s1);
      if (lane == 0) atomicAdd(&gcnt[b], 4.0f);
    }
  } else {
    atomicAdd(&gsum[b*DD + lane*2],     h0);
    atomicAdd(&gsum[b*DD + lane*2 + 1], h1);
    if (lane == 0) atomicAdd(&gcnt[b], 1.0f);
  }
}

// ---------------- pool-divide + adapter + layernorm ----------------
__global__ __launch_bounds__(128)
void k_pool(const float* __restrict__ gsum, const float* __restrict__ gcnt,
            const float* __restrict__ aW, const float* __restrict__ ab,
            const float* __restrict__ ng, const float* __restrict__ nb,
            float* __restrict__ g_ln)
{
  __shared__ float row[128];
  __shared__ float red[128];
  const int g = blockIdx.x, d = threadIdx.x;
  float denom = fmaxf(gcnt[g], 1.0f);
  row[d] = gsum[g*DD + d] / denom;
  __syncthreads();
  double accd = (double)ab[d];
  for (int k = 0; k < 128; ++k) accd += (double)row[k] * (double)aW[k*DD + d];
  float a = (float)accd;
  red[d] = a; __syncthreads();
  for (int s = 64; s > 0; s >>= 1){ if (d < s) red[d] += red[d+s]; __syncthreads(); }
  float mean = red[0] / 128.f; __syncthreads();
  float c = a - mean;
  red[d] = c*c; __syncthreads();
  for (int s = 64; s > 0; s >>= 1){ if (d < s) red[d] += red[d+s]; __syncthreads(); }
  float var = red[0] / 128.f; __syncthreads();
  float inv = (float)(1.0 / sqrt((double)var + (double)LN_EPS));
  g_ln[g*DD + d] = c * inv * ng[d] + nb[d];
}

// ---------------- residual VQ (Q=3, K=512) ----------------
__global__ __launch_bounds__(256)
void k_rvq(const float* __restrict__ g_ln, const float* __restrict__ codebooks,
           float* __restrict__ ind_out, int* __restrict__ idx_i,
           float* __restrict__ accs)
{
  __shared__ __align__(16) float r_lds[128];
  __shared__ float red[128];
  __shared__ double bd[64];
  __shared__ int bi[64];
  __shared__ int chosen;
  const int g = blockIdx.x, tid = threadIdx.x;
  if (tid < 128) r_lds[tid] = g_ln[g*DD + tid];
  __syncthreads();
  const int cl = tid >> 2, dq = tid & 3;
  for (int q = 0; q < Q_QUANT; ++q){
    const float* cb = codebooks + (size_t)q * K_CODES * DD;
    double bestd = 1e300; int besti = 1 << 30;
    for (int r = 0; r < 8; ++r){
      int c = r*64 + cl;
      double rc = 0.0, cc = 0.0;
      const float4* cp = (const float4*)&cb[c*DD + dq*32];
      const float4* rp = (const float4*)&r_lds[dq*32];
#pragma unroll
      for (int i = 0; i < 8; ++i){
        float4 cv = cp[i]; float4 rv = rp[i];
        rc += (double)cv.x*rv.x + (double)cv.y*rv.y + (double)cv.z*rv.z + (double)cv.w*rv.w;
        cc += (double)cv.x*cv.x + (double)cv.y*cv.y + (double)cv.z*cv.z + (double)cv.w*cv.w;
      }
      rc += __shfl_xor(rc, 1); rc += __shfl_xor(rc, 2);
      cc += __shfl_xor(cc, 1); cc += __shfl_xor(cc, 2);
      if (dq == 0){
        double d2 = cc - 2.0*rc;
        if (d2 < bestd || (d2 == bestd && c < besti)){ bestd = d2; besti = c; }
      }
    }
    if (dq == 0){ bd[cl] = bestd; bi[cl] = besti; }
    __syncthreads();
    if (tid < 64){
      double d2 = bd[tid]; int ii = bi[tid];
#pragma unroll
      for (int m = 1; m < 64; m <<= 1){
        double od = __shfl_xor(d2, m); int oi = __shfl_xor(ii, m);
        if (od < d2 || (od == d2 && oi < ii)){ d2 = od; ii = oi; }
      }
      if (tid == 0) chosen = ii;
    }
    __syncthreads();
    const int idx = chosen;
    if (tid == 0){
      ind_out[g*Q_QUANT + q] = (float)idx;
      idx_i[g*Q_QUANT + q] = idx;
    }
    if (tid < 128){
      float cd = cb[idx*DD + tid];
      float diff = cd - r_lds[tid];
      red[tid] = diff * diff;
      r_lds[tid] -= cd;
    }
    __syncthreads();
    for (int s = 64; s > 0; s >>= 1){ if (tid < s) red[tid] += red[tid+s]; __syncthreads(); }
    if (tid == 0) atomicAdd(&accs[q], red[0]);
    __syncthreads();
  }
  if (tid < 128) red[tid] = r_lds[tid]*r_lds[tid];
  __syncthreads();
  for (int s = 64; s > 0; s >>= 1){ if (tid < s) red[tid] += red[tid+s]; __syncthreads(); }
  if (tid == 0) atomicAdd(&accs[3], red[0]);
}

// ---------------- tokens: LN(code @ out_W + out_b) ----------------
__global__ __launch_bounds__(256)
void k_tokens(const float* __restrict__ codebooks, const int* __restrict__ idx_i,
              const float* __restrict__ out_W, const float* __restrict__ out_b,
              const float* __restrict__ og, const float* __restrict__ ob,
              float* __restrict__ tokens)
{
  __shared__ __align__(16) float c_lds[128];
  __shared__ float red[256];
  const int blk = blockIdx.x;
  const int g = blk / 3, q = blk % 3;
  const int tid = threadIdx.x;
  const int idx = idx_i[g*Q_QUANT + q];
  if (tid < 128) c_lds[tid] = codebooks[((size_t)q*K_CODES + idx)*DD + tid];
  __syncthreads();
  double v0 = (double)out_b[tid];
  double v1 = (double)out_b[tid + 256];
  for (int k = 0; k < 128; ++k){
    double ck = (double)c_lds[k];
    v0 += ck * (double)out_W[k*FD_OUT + tid];
    v1 += ck * (double)out_W[k*FD_OUT + tid + 256];
  }
  float f0 = (float)v0, f1 = (float)v1;
  red[tid] = f0 + f1; __syncthreads();
  for (int s = 128; s > 0; s >>= 1){ if (tid < s) red[tid] += red[tid+s]; __syncthreads(); }
  float mean = red[0] / 512.f; __syncthreads();
  float d0 = f0 - mean, d1 = f1 - mean;
  red[tid] = d0*d0 + d1*d1; __syncthreads();
  for (int s = 128; s > 0; s >>= 1){ if (tid < s) red[tid] += red[tid+s]; __syncthreads(); }
  float var = red[0] / 512.f; __syncthreads();
  float inv = (float)(1.0 / sqrt((double)var + (double)LN_EPS));
  tokens[(size_t)blk*FD_OUT + tid]       = d0*inv*og[tid] + ob[tid];
  tokens[(size_t)blk*FD_OUT + tid + 256] = d1*inv*og[tid+256] + ob[tid+256];
}

// ---------------- loss ----------------
__global__ void k_loss(const float* __restrict__ accs, float* __restrict__ out)
{
  float commit = (accs[0] + accs[1] + accs[2]) / (3.0f * G_GRAPHS * DD);
  float resid  = accs[3] / ((float)G_GRAPHS * DD);
  out[0] = commit + resid;
}

extern "C" void kernel_launch(void* const* d_in, const int* in_sizes, int n_in,
                              void* d_out, int out_size, void* d_ws, size_t ws_size,
                              hipStream_t stream)
{
  (void)in_sizes; (void)n_in; (void)out_size; (void)ws_size;
  const float* x         = (const float*)d_in[0];
  const int*   ei        = (const int*)d_in[1];
  const float* edge_attr = (const float*)d_in[2];
  const int*   batch_vec = (const int*)d_in[3];
  const float* W_l       = (const float*)d_in[4];
  const float* b_l       = (const float*)d_in[5];
  const float* W_r       = (const float*)d_in[6];
  const float* b_r       = (const float*)d_in[7];
  const float* W_edge    = (const float*)d_in[8];
  const float* att       = (const float*)d_in[9];
  const float* conv_bias = (const float*)d_in[10];
  const float* aW        = (const float*)d_in[11];
  const float* ab        = (const float*)d_in[12];
  const float* ng        = (const float*)d_in[13];
  const float* nb        = (const float*)d_in[14];
  const float* codebooks = (const float*)d_in[15];
  const float* out_W     = (const float*)d_in[16];
  const float* out_b     = (const float*)d_in[17];
  const float* og        = (const float*)d_in[18];
  const float* ob        = (const float*)d_in[19];
  float* outf = (float*)d_out;

  char* w = (char*)d_ws;
  size_t o = 0;
  auto nxt = [&](size_t bytes)->void*{
    void* p = w + o;
    o += (bytes + 511) & ~(size_t)511;
    return p;
  };
  // --- zeroed buffers first (single memset over the span) ---
  int*   indeg    = (int*)  nxt((size_t)N_NODES*4);
  int*   pos      = (int*)  nxt((size_t)N_NODES*4);
  float* asum_mid = (float*)nxt((size_t)64*DD*4);
  float* gsum     = (float*)nxt((size_t)G_GRAPHS*DD*4);
  float* gcnt     = (float*)nxt((size_t)G_GRAPHS*4);
  float* accs     = (float*)nxt(16);
  const size_t zero_span = o;
  // --- non-zeroed ---
  int*   off      = (int*)  nxt((size_t)(N_NODES+1)*4);
  float* xl       = (float*)nxt((size_t)N_NODES*DD*4);
  float* xr       = (float*)nxt((size_t)N_NODES*DD*4);
  uint2* rec      = (uint2*)nxt((size_t)E_EDGES*8);
  float* me       = (float*)nxt((size_t)DD*4);
  float* g_ln     = (float*)nxt((size_t)G_GRAPHS*DD*4);
  int*   idx_i    = (int*)  nxt((size_t)G_GRAPHS*Q_QUANT*4);
  int*   bsum     = (int*)  nxt((size_t)SC_NB*4);
  int*   boff     = (int*)  nxt((size_t)SC_NB*4);

  hipMemsetAsync(w, 0, zero_span, stream);

  k_hist<<<dim3((E_EDGES+255)/256), dim3(256), 0, stream>>>(ei, indeg);
  k_scan1<<<dim3(SC_NB), dim3(512), 0, stream>>>(indeg, off, bsum);
  k_scan2<<<dim3(1), dim3(128), 0, stream>>>(bsum, boff);
  k_scan3<<<dim3(SC_NB), dim3(512), 0, stream>>>(off, boff);
  k_xform2<<<dim3((N_NODES+63)/64), dim3(256), 0, stream>>>(x, W_l, b_l, W_r, b_r,
                                                            xl, xr, N_NODES);
  k_edge<<<dim3(E_EDGES/64), dim3(256), 0, stream>>>(edge_attr, W_edge, ei, xl, xr, att,
                                                     off, pos, rec, asum_mid);
  k_me<<<dim3(1), dim3(128), 0, stream>>>(asum_mid, W_edge, me);
  k_aggregate<<<dim3(N_NODES/4), dim3(256), 0, stream>>>(off, rec, xl, xr, me, att,
                                                         conv_bias, batch_vec, gsum, gcnt);
  k_pool<<<dim3(G_GRAPHS), dim3(128), 0, stream>>>(gsum, gcnt, aW, ab, ng, nb, g_ln);
  k_rvq<<<dim3(G_GRAPHS), dim3(256), 0, stream>>>(g_ln, codebooks,
                                                  outf + (size_t)G_GRAPHS*Q_QUANT*FD_OUT,
                                                  idx_i, accs);
  k_tokens<<<dim3(G_GRAPHS*Q_QUANT), dim3(256), 0, stream>>>(codebooks, idx_i, out_W, out_b,
                                                             og, ob, outf);
  k_loss<<<dim3(1), dim3(1), 0, stream>>>(accs,
                                          outf + (size_t)G_GRAPHS*Q_QUANT*FD_OUT
                                               + (size_t)G_GRAPHS*Q_QUANT);
}